// Round 10
// baseline (594.085 us; speedup 1.0000x reference)
//
#include <hip/hip_runtime.h>

// TransformerConv x2 on MI355X — 32x32 MFMA GEMM + degree-sorted 16-lane
// gather attention over interleaved kv, 4-B compressed CSR.
// N=50000, E=800000, H=4, C=32, D=128.

#define TPB 256

typedef __attribute__((ext_vector_type(8))) short short8v;
typedef __attribute__((ext_vector_type(8))) unsigned short ushort8v;
typedef __attribute__((ext_vector_type(16))) float f32x16;

__device__ __forceinline__ unsigned short f2bf(float f) {
    unsigned u = __float_as_uint(f);
    u = (u + 0x7FFFu + ((u >> 16) & 1u)) >> 16;
    return (unsigned short)u;
}
__device__ __forceinline__ float bf2f(unsigned short s) {
    return __uint_as_float((unsigned)s << 16);
}
__device__ __forceinline__ float exp2_hw(float x) {
    float r;
    asm("v_exp_f32 %0, %1" : "=v"(r) : "v"(x));
    return r;
}

// ---- fused: weight prepack (32x32 B-fragments) + x fp32->bf16 convert ----
__global__ void __launch_bounds__(TPB) prep_cvt_k(
    const float* __restrict__ Wq1, const float* __restrict__ Wk1,
    const float* __restrict__ Wv1, const float* __restrict__ Ws1,
    const float* __restrict__ Wq2, const float* __restrict__ Wk2,
    const float* __restrict__ Wv2, const float* __restrict__ Ws2,
    unsigned short* __restrict__ pack,
    const float* __restrict__ x, unsigned short* __restrict__ xb, int n4)
{
    if (blockIdx.x < 512) {
        int i = blockIdx.x * TPB + threadIdx.x;   // 131072 total
        int j = i & 7, lane = (i >> 3) & 63, t = (i >> 9) & 7, nc = (i >> 12) & 3, g = (i >> 14) & 7;
        const float* Wt[8] = {Wq1, Wk1, Wv1, Ws1, Wq2, Wk2, Wv2, Ws2};
        const float* W = Wt[g];
        int kk = t * 16 + (lane >> 5) * 8 + j;
        int nn = nc * 32 + (lane & 31);
        pack[i] = f2bf(W[kk * 128 + nn]);
    } else {
        int i = (blockIdx.x - 512) * TPB + threadIdx.x;
        if (i >= n4) return;
        float4 v = *(const float4*)(x + (size_t)i * 4);
        ushort4 o;
        o.x = f2bf(v.x); o.y = f2bf(v.y); o.z = f2bf(v.z); o.w = f2bf(v.w);
        *(ushort4*)(xb + (size_t)i * 4) = o;
    }
}

// ---- MFMA GEMM (32x32x16): g=blockIdx.y: 0->q, 1->kv k-half, 2->kv v-half,
//      3->skip fp32 ----
__global__ void __launch_bounds__(TPB) gemm_mfma_k(
    const unsigned short* __restrict__ A, int M,
    const unsigned short* __restrict__ pack,
    const float* __restrict__ bq, const float* __restrict__ bk,
    const float* __restrict__ bv, const float* __restrict__ bs,
    unsigned short* __restrict__ oq, unsigned short* __restrict__ okv,
    float* __restrict__ os)
{
    const int g = blockIdx.y;
    const int row0 = blockIdx.x * 128;
    const int wv = threadIdx.x >> 6;
    const int lane = threadIdx.x & 63;
    const int rbase = row0 + wv * 32;
    const int arow = rbase + (lane & 31);
    const int kh = (lane >> 5) * 8;

    const short8v z8 = {0, 0, 0, 0, 0, 0, 0, 0};
    short8v a[8];
    if (arow < M) {
        const unsigned short* Ap = A + (size_t)arow * 128 + kh;
#pragma unroll
        for (int t = 0; t < 8; ++t) a[t] = *(const short8v*)(Ap + t * 16);
    } else {
#pragma unroll
        for (int t = 0; t < 8; ++t) a[t] = z8;
    }

    f32x16 acc[4];
#pragma unroll
    for (int nc = 0; nc < 4; ++nc)
#pragma unroll
        for (int r = 0; r < 16; ++r) acc[nc][r] = 0.f;

    const unsigned short* bp = pack + (size_t)g * 16384;
#pragma unroll
    for (int nc = 0; nc < 4; ++nc) {
#pragma unroll
        for (int t = 0; t < 8; ++t) {
            short8v b = *(const short8v*)(bp + (nc * 8 + t) * 512 + lane * 8);
            acc[nc] = __builtin_amdgcn_mfma_f32_32x32x16_bf16(a[t], b, acc[nc], 0, 0, 0);
        }
    }

    const float* bias = g == 0 ? bq : (g == 1 ? bk : (g == 2 ? bv : bs));
    const int col = lane & 31;
    const int rb2 = rbase + 4 * (lane >> 5);
    if (g == 3) {
#pragma unroll
        for (int nc = 0; nc < 4; ++nc) {
            float bb = bias[nc * 32 + col];
#pragma unroll
            for (int r = 0; r < 16; ++r) {
                int row = rb2 + (r & 3) + 8 * (r >> 2);
                if (row < M) os[(size_t)row * 128 + nc * 32 + col] = acc[nc][r] + bb;
            }
        }
    } else {
        unsigned short* out = g == 0 ? oq : okv;
        const int stride = g == 0 ? 128 : 256;
        const int goff = g == 2 ? 128 : 0;
#pragma unroll
        for (int nc = 0; nc < 4; ++nc) {
            float bb = bias[nc * 32 + col];
#pragma unroll
            for (int r = 0; r < 16; ++r) {
                int row = rb2 + (r & 3) + 8 * (r >> 2);
                if (row < M)
                    out[(size_t)row * stride + goff + nc * 32 + col] = f2bf(acc[nc][r] + bb);
            }
        }
    }
}

// ---------------- CSR build + degree counting-sort ----------------
__global__ void __launch_bounds__(TPB) hist_k(const int* __restrict__ dst,
                                              int* __restrict__ deg, int E)
{
    int e = blockIdx.x * TPB + threadIdx.x;
    if (e < E) atomicAdd(&deg[dst[e]], 1);
}

// scan_a: per-1024-block inclusive scan of deg; also histogram degrees.
__global__ void __launch_bounds__(TPB) scan_a_k(const int* __restrict__ deg, int n,
                                                int* __restrict__ incl,
                                                int* __restrict__ bsum,
                                                int* __restrict__ dhist)
{
    __shared__ int ts[TPB];
    const int base = blockIdx.x * 1024;
    int vals[4], s = 0;
#pragma unroll
    for (int j = 0; j < 4; ++j) {
        int i = base + threadIdx.x * 4 + j;
        vals[j] = (i < n) ? deg[i] : 0;
        s += vals[j];
        if (i < n) atomicAdd(&dhist[min(vals[j], 1023)], 1);
    }
    ts[threadIdx.x] = s;
    __syncthreads();
    for (int off = 1; off < TPB; off <<= 1) {
        int u = (threadIdx.x >= off) ? ts[threadIdx.x - off] : 0;
        __syncthreads();
        ts[threadIdx.x] += u;
        __syncthreads();
    }
    int run = ts[threadIdx.x] - s;
#pragma unroll
    for (int j = 0; j < 4; ++j) {
        run += vals[j];
        int i = base + threadIdx.x * 4 + j;
        if (i < n) incl[i] = run;
    }
    if (threadIdx.x == TPB - 1) bsum[blockIdx.x] = ts[TPB - 1];
}

// scan_b: exclusive scan of bsum (nb<=256) + inclusive scan of dhist (1024).
__global__ void __launch_bounds__(TPB) scan_b_k(int* __restrict__ bsum, int nb,
                                                int* __restrict__ dhist)
{
    __shared__ int ts[TPB];
    int t = threadIdx.x;
    int v = (t < nb) ? bsum[t] : 0;
    ts[t] = v;
    __syncthreads();
    for (int off = 1; off < TPB; off <<= 1) {
        int u = (t >= off) ? ts[t - off] : 0;
        __syncthreads();
        ts[t] += u;
        __syncthreads();
    }
    if (t < nb) bsum[t] = ts[t] - v;
    __syncthreads();

    // dhist inclusive scan: 1024 elems, 4 per thread
    int vals[4], s = 0;
#pragma unroll
    for (int j = 0; j < 4; ++j) {
        vals[j] = dhist[t * 4 + j];
        s += vals[j];
    }
    __syncthreads();
    ts[t] = s;
    __syncthreads();
    for (int off = 1; off < TPB; off <<= 1) {
        int u = (t >= off) ? ts[t - off] : 0;
        __syncthreads();
        ts[t] += u;
        __syncthreads();
    }
    int run = ts[t] - s;
#pragma unroll
    for (int j = 0; j < 4; ++j) {
        run += vals[j];
        dhist[t * 4 + j] = run;
    }
}

// finalize: row_ptr/cursor + degree-sorted (descending) permutation scatter.
__global__ void __launch_bounds__(TPB) finalize_k(const int* __restrict__ incl,
                                                  const int* __restrict__ deg,
                                                  const int* __restrict__ bsum, int n,
                                                  int* __restrict__ row_ptr,
                                                  int* __restrict__ cursor,
                                                  const int* __restrict__ dhist,
                                                  int* __restrict__ dcur,
                                                  int* __restrict__ perm)
{
    const int base = blockIdx.x * 1024;
    const int boff = bsum[blockIdx.x];
#pragma unroll
    for (int j = 0; j < 4; ++j) {
        int i = base + threadIdx.x * 4 + j;
        if (i < n) {
            int dg = deg[i];
            int iv = incl[i] + boff;
            int st = iv - dg;
            row_ptr[i] = st;
            cursor[i] = st;
            if (i == n - 1) row_ptr[n] = iv;
            int db = min(dg, 1023);
            int pos = (n - dhist[db]) + atomicAdd(&dcur[db], 1);
            perm[pos] = i;
        }
    }
}

__global__ void __launch_bounds__(TPB) scatter_k(
    const int* __restrict__ src, const int* __restrict__ dst,
    const float* __restrict__ ea, int* __restrict__ cursor,
    unsigned* __restrict__ csr_pack, int E)
{
    int e = blockIdx.x * TPB + threadIdx.x;
    if (e >= E) return;
    int pos = atomicAdd(&cursor[dst[e]], 1);
    csr_pack[pos] = ((unsigned)f2bf(ea[e]) << 16) | (unsigned)src[e];
}

// ---- gather attention: 16 lanes/node, degree-sorted perm, packed CSR ----
template <bool BF16OUT>
__global__ void __launch_bounds__(TPB) node_attn_k(
    const unsigned short* __restrict__ q, const unsigned short* __restrict__ kv,
    const float* __restrict__ skip, const float* __restrict__ We,
    const int* __restrict__ row_ptr, const unsigned* __restrict__ csr_pack,
    const int* __restrict__ perm,
    void* __restrict__ outp, int n)
{
    const int slot = blockIdx.x * 16 + (threadIdx.x >> 4);
    if (slot >= n) return;
    const int node = perm[slot];
    const int l16 = threadIdx.x & 15;
    const int c8 = l16 * 8;

    const float C2 = 0.17677669529663687f * 1.44269504088896f; // 1/sqrt(32)*log2e

    float we8[8], qv[8];
    {
        float4 wlo = *(const float4*)(We + c8);
        float4 whi = *(const float4*)(We + c8 + 4);
        we8[0] = wlo.x; we8[1] = wlo.y; we8[2] = wlo.z; we8[3] = wlo.w;
        we8[4] = whi.x; we8[5] = whi.y; we8[6] = whi.z; we8[7] = whi.w;
        ushort8v qu = *(const ushort8v*)(q + (size_t)node * 128 + c8);
#pragma unroll
        for (int i = 0; i < 8; ++i) qv[i] = bf2f((unsigned short)qu[i]) * C2;
    }

    float qwe = 0.f;
#pragma unroll
    for (int i = 0; i < 8; ++i) qwe = fmaf(qv[i], we8[i], qwe);
    qwe += __shfl_xor(qwe, 1);
    qwe += __shfl_xor(qwe, 2);

    const int p0 = row_ptr[node], p1 = row_ptr[node + 1];

    float m = -3.4e38f, l = 0.f, sae = 0.f;
    float acc[8];
#pragma unroll
    for (int i = 0; i < 8; ++i) acc[i] = 0.f;

    for (int j = p0; j < p1; j += 4) {
        const int last = p1 - 1;
        unsigned pr0 = csr_pack[j];
        unsigned pr1 = csr_pack[min(j + 1, last)];
        unsigned pr2 = csr_pack[min(j + 2, last)];
        unsigned pr3 = csr_pack[min(j + 3, last)];
        const unsigned short* b0 = kv + (pr0 & 0xFFFFu) * 256u + c8;
        const unsigned short* b1 = kv + (pr1 & 0xFFFFu) * 256u + c8;
        const unsigned short* b2 = kv + (pr2 & 0xFFFFu) * 256u + c8;
        const unsigned short* b3 = kv + (pr3 & 0xFFFFu) * 256u + c8;
        ushort8v ku0 = *(const ushort8v*)b0;
        ushort8v ku1 = *(const ushort8v*)b1;
        ushort8v ku2 = *(const ushort8v*)b2;
        ushort8v ku3 = *(const ushort8v*)b3;
        ushort8v vu0 = *(const ushort8v*)(b0 + 128);
        ushort8v vu1 = *(const ushort8v*)(b1 + 128);
        ushort8v vu2 = *(const ushort8v*)(b2 + 128);
        ushort8v vu3 = *(const ushort8v*)(b3 + 128);

        float d0 = 0.f, d1 = 0.f, d2 = 0.f, d3 = 0.f;
#pragma unroll
        for (int i = 0; i < 8; ++i) {
            d0 = fmaf(bf2f((unsigned short)ku0[i]), qv[i], d0);
            d1 = fmaf(bf2f((unsigned short)ku1[i]), qv[i], d1);
            d2 = fmaf(bf2f((unsigned short)ku2[i]), qv[i], d2);
            d3 = fmaf(bf2f((unsigned short)ku3[i]), qv[i], d3);
        }
        d0 += __shfl_xor(d0, 1); d0 += __shfl_xor(d0, 2);
        d1 += __shfl_xor(d1, 1); d1 += __shfl_xor(d1, 2);
        d2 += __shfl_xor(d2, 1); d2 += __shfl_xor(d2, 2);
        d3 += __shfl_xor(d3, 1); d3 += __shfl_xor(d3, 2);

        float ea0 = bf2f((unsigned short)(pr0 >> 16));
        float ea1 = bf2f((unsigned short)(pr1 >> 16));
        float ea2 = bf2f((unsigned short)(pr2 >> 16));
        float ea3 = bf2f((unsigned short)(pr3 >> 16));
        float al0 = fmaf(ea0, qwe, d0);
        float al1 = (j + 1 < p1) ? fmaf(ea1, qwe, d1) : -3.4e38f;
        float al2 = (j + 2 < p1) ? fmaf(ea2, qwe, d2) : -3.4e38f;
        float al3 = (j + 3 < p1) ? fmaf(ea3, qwe, d3) : -3.4e38f;

        float mn = fmaxf(m, fmaxf(fmaxf(al0, al1), fmaxf(al2, al3)));
        float sc = exp2_hw(m - mn);
        float pe0 = exp2_hw(al0 - mn), pe1 = exp2_hw(al1 - mn);
        float pe2 = exp2_hw(al2 - mn), pe3 = exp2_hw(al3 - mn);

        l = fmaf(l, sc, (pe0 + pe1) + (pe2 + pe3));
        sae = fmaf(sae, sc, fmaf(pe3, ea3, fmaf(pe2, ea2, fmaf(pe1, ea1, pe0 * ea0))));
#pragma unroll
        for (int i = 0; i < 8; ++i) {
            float mv = fmaf(pe0, bf2f((unsigned short)vu0[i]),
                       fmaf(pe1, bf2f((unsigned short)vu1[i]),
                       fmaf(pe2, bf2f((unsigned short)vu2[i]),
                            pe3 * bf2f((unsigned short)vu3[i]))));
            acc[i] = fmaf(acc[i], sc, mv);
        }
        m = mn;
    }

    float inv = 1.f / (l + 1e-16f);
    float4 sklo = *(const float4*)(skip + (size_t)node * 128 + c8);
    float4 skhi = *(const float4*)(skip + (size_t)node * 128 + c8 + 4);
    float sk[8] = {sklo.x, sklo.y, sklo.z, sklo.w, skhi.x, skhi.y, skhi.z, skhi.w};
    float o[8];
#pragma unroll
    for (int i = 0; i < 8; ++i)
        o[i] = fmaxf(fmaf(fmaf(sae, we8[i], acc[i]), inv, sk[i]), 0.f);

    if (BF16OUT) {
        ushort8v ov;
#pragma unroll
        for (int i = 0; i < 8; ++i) ov[i] = f2bf(o[i]);
        *(ushort8v*)((unsigned short*)outp + (size_t)node * 128 + c8) = ov;
    } else {
        float* op = (float*)outp + (size_t)node * 128 + c8;
        *(float4*)op = make_float4(o[0], o[1], o[2], o[3]);
        *(float4*)(op + 4) = make_float4(o[4], o[5], o[6], o[7]);
    }
}

extern "C" void kernel_launch(void* const* d_in, const int* in_sizes, int n_in,
                              void* d_out, int out_size, void* d_ws, size_t ws_size,
                              hipStream_t stream)
{
    const float* x   = (const float*)d_in[0];
    const int*   ei  = (const int*)d_in[1];
    const float* ea  = (const float*)d_in[2];
    const float* Wq1 = (const float*)d_in[3];  const float* bq1 = (const float*)d_in[4];
    const float* Wk1 = (const float*)d_in[5];  const float* bk1 = (const float*)d_in[6];
    const float* Wv1 = (const float*)d_in[7];  const float* bv1 = (const float*)d_in[8];
    const float* We1 = (const float*)d_in[9];
    const float* Ws1 = (const float*)d_in[10]; const float* bs1 = (const float*)d_in[11];
    const float* Wq2 = (const float*)d_in[12]; const float* bq2 = (const float*)d_in[13];
    const float* Wk2 = (const float*)d_in[14]; const float* bk2 = (const float*)d_in[15];
    const float* Wv2 = (const float*)d_in[16]; const float* bv2 = (const float*)d_in[17];
    const float* We2 = (const float*)d_in[18];
    const float* Ws2 = (const float*)d_in[19]; const float* bs2 = (const float*)d_in[20];

    const int N = in_sizes[0] / 128;
    const int E = in_sizes[1] / 2;
    const int* src = ei;
    const int* dst = ei + E;
    float* outf = (float*)d_out;

    // workspace layout
    unsigned short* q  = (unsigned short*)d_ws;          // N*128 bf16
    unsigned short* kv = q + (size_t)N * 128;            // N*256 bf16 (k|v)
    float*          s  = (float*)(kv + (size_t)N * 256); // N*128 f32 skip
    unsigned short* xb = (unsigned short*)(s + (size_t)N * 128); // bf16 x / h
    unsigned short* pk = xb + (size_t)N * 128;           // 131072 (both layers)
    int*   row_ptr = (int*)(pk + 131072);                // N+1
    int*   deg     = row_ptr + (N + 1);                  // N      (memset...
    int*   dhist   = deg + N;                            // 1024    ...these
    int*   dcur    = dhist + 1024;                       // 1024    three)
    int*   incl    = dcur + 1024;                        // N
    int*   cursor  = incl + N;                           // N
    int*   bsum    = cursor + N;                         // 256
    int*   perm    = bsum + 256;                         // N
    unsigned* csr_pack = (unsigned*)(perm + N);          // E

    const int gE   = (E + TPB - 1) / TPB;
    const int nb   = (N + 1023) / 1024;
    const int gN16 = (N + 15) / 16;
    const int n4   = N * 128 / 4;
    const int gPC  = 512 + (n4 + TPB - 1) / TPB;
    const int gG   = (N + 127) / 128;
    const dim3 gGd(gG, 4);

    // ---- CSR build + degree sort (shared by both layers) ----
    hipMemsetAsync(deg, 0, (size_t)(N + 2048) * sizeof(int), stream);
    hist_k<<<gE, TPB, 0, stream>>>(dst, deg, E);
    scan_a_k<<<nb, TPB, 0, stream>>>(deg, N, incl, bsum, dhist);
    scan_b_k<<<1, TPB, 0, stream>>>(bsum, nb, dhist);
    finalize_k<<<nb, TPB, 0, stream>>>(incl, deg, bsum, N, row_ptr, cursor,
                                       dhist, dcur, perm);
    scatter_k<<<gE, TPB, 0, stream>>>(src, dst, ea, cursor, csr_pack, E);

    // ---- weight prepack (both layers) + x convert ----
    prep_cvt_k<<<gPC, TPB, 0, stream>>>(Wq1, Wk1, Wv1, Ws1, Wq2, Wk2, Wv2, Ws2,
                                        pk, x, xb, n4);

    // ---- layer 1 ----
    gemm_mfma_k<<<gGd, TPB, 0, stream>>>(xb, N, pk, bq1, bk1, bv1, bs1, q, kv, s);
    node_attn_k<true><<<gN16, TPB, 0, stream>>>(q, kv, s, We1, row_ptr, csr_pack,
                                                perm, xb, N);
    // ---- layer 2 ----
    gemm_mfma_k<<<gGd, TPB, 0, stream>>>(xb, N, pk + 65536, bq2, bk2, bv2, bs2,
                                         q, kv, s);
    node_attn_k<false><<<gN16, TPB, 0, stream>>>(q, kv, s, We2, row_ptr, csr_pack,
                                                 perm, outf, N);
}

// Round 11
// 324.693 us; speedup vs baseline: 1.8297x; 1.8297x over previous
//
#include <hip/hip_runtime.h>

// TransformerConv x2 on MI355X — 32x32 MFMA GEMM + degree-sorted 16-lane
// gather attention over interleaved kv, 4-B compressed CSR.
// Degree sort via contention-free two-level counting sort.
// N=50000, E=800000, H=4, C=32, D=128.

#define TPB 256

typedef __attribute__((ext_vector_type(8))) short short8v;
typedef __attribute__((ext_vector_type(8))) unsigned short ushort8v;
typedef __attribute__((ext_vector_type(16))) float f32x16;

__device__ __forceinline__ unsigned short f2bf(float f) {
    unsigned u = __float_as_uint(f);
    u = (u + 0x7FFFu + ((u >> 16) & 1u)) >> 16;
    return (unsigned short)u;
}
__device__ __forceinline__ float bf2f(unsigned short s) {
    return __uint_as_float((unsigned)s << 16);
}
__device__ __forceinline__ float exp2_hw(float x) {
    float r;
    asm("v_exp_f32 %0, %1" : "=v"(r) : "v"(x));
    return r;
}

// ---- fused: weight prepack (32x32 B-fragments) + x fp32->bf16 convert ----
__global__ void __launch_bounds__(TPB) prep_cvt_k(
    const float* __restrict__ Wq1, const float* __restrict__ Wk1,
    const float* __restrict__ Wv1, const float* __restrict__ Ws1,
    const float* __restrict__ Wq2, const float* __restrict__ Wk2,
    const float* __restrict__ Wv2, const float* __restrict__ Ws2,
    unsigned short* __restrict__ pack,
    const float* __restrict__ x, unsigned short* __restrict__ xb, int n4)
{
    if (blockIdx.x < 512) {
        int i = blockIdx.x * TPB + threadIdx.x;   // 131072 total
        int j = i & 7, lane = (i >> 3) & 63, t = (i >> 9) & 7, nc = (i >> 12) & 3, g = (i >> 14) & 7;
        const float* Wt[8] = {Wq1, Wk1, Wv1, Ws1, Wq2, Wk2, Wv2, Ws2};
        const float* W = Wt[g];
        int kk = t * 16 + (lane >> 5) * 8 + j;
        int nn = nc * 32 + (lane & 31);
        pack[i] = f2bf(W[kk * 128 + nn]);
    } else {
        int i = (blockIdx.x - 512) * TPB + threadIdx.x;
        if (i >= n4) return;
        float4 v = *(const float4*)(x + (size_t)i * 4);
        ushort4 o;
        o.x = f2bf(v.x); o.y = f2bf(v.y); o.z = f2bf(v.z); o.w = f2bf(v.w);
        *(ushort4*)(xb + (size_t)i * 4) = o;
    }
}

// ---- MFMA GEMM (32x32x16): g=blockIdx.y: 0->q, 1->kv k-half, 2->kv v-half,
//      3->skip fp32 ----
__global__ void __launch_bounds__(TPB) gemm_mfma_k(
    const unsigned short* __restrict__ A, int M,
    const unsigned short* __restrict__ pack,
    const float* __restrict__ bq, const float* __restrict__ bk,
    const float* __restrict__ bv, const float* __restrict__ bs,
    unsigned short* __restrict__ oq, unsigned short* __restrict__ okv,
    float* __restrict__ os)
{
    const int g = blockIdx.y;
    const int row0 = blockIdx.x * 128;
    const int wv = threadIdx.x >> 6;
    const int lane = threadIdx.x & 63;
    const int rbase = row0 + wv * 32;
    const int arow = rbase + (lane & 31);
    const int kh = (lane >> 5) * 8;

    const short8v z8 = {0, 0, 0, 0, 0, 0, 0, 0};
    short8v a[8];
    if (arow < M) {
        const unsigned short* Ap = A + (size_t)arow * 128 + kh;
#pragma unroll
        for (int t = 0; t < 8; ++t) a[t] = *(const short8v*)(Ap + t * 16);
    } else {
#pragma unroll
        for (int t = 0; t < 8; ++t) a[t] = z8;
    }

    f32x16 acc[4];
#pragma unroll
    for (int nc = 0; nc < 4; ++nc)
#pragma unroll
        for (int r = 0; r < 16; ++r) acc[nc][r] = 0.f;

    const unsigned short* bp = pack + (size_t)g * 16384;
#pragma unroll
    for (int nc = 0; nc < 4; ++nc) {
#pragma unroll
        for (int t = 0; t < 8; ++t) {
            short8v b = *(const short8v*)(bp + (nc * 8 + t) * 512 + lane * 8);
            acc[nc] = __builtin_amdgcn_mfma_f32_32x32x16_bf16(a[t], b, acc[nc], 0, 0, 0);
        }
    }

    const float* bias = g == 0 ? bq : (g == 1 ? bk : (g == 2 ? bv : bs));
    const int col = lane & 31;
    const int rb2 = rbase + 4 * (lane >> 5);
    if (g == 3) {
#pragma unroll
        for (int nc = 0; nc < 4; ++nc) {
            float bb = bias[nc * 32 + col];
#pragma unroll
            for (int r = 0; r < 16; ++r) {
                int row = rb2 + (r & 3) + 8 * (r >> 2);
                if (row < M) os[(size_t)row * 128 + nc * 32 + col] = acc[nc][r] + bb;
            }
        }
    } else {
        unsigned short* out = g == 0 ? oq : okv;
        const int stride = g == 0 ? 128 : 256;
        const int goff = g == 2 ? 128 : 0;
#pragma unroll
        for (int nc = 0; nc < 4; ++nc) {
            float bb = bias[nc * 32 + col];
#pragma unroll
            for (int r = 0; r < 16; ++r) {
                int row = rb2 + (r & 3) + 8 * (r >> 2);
                if (row < M)
                    out[(size_t)row * stride + goff + nc * 32 + col] = f2bf(acc[nc][r] + bb);
            }
        }
    }
}

// ---------------- CSR build + two-level degree counting-sort ----------------
__global__ void __launch_bounds__(TPB) hist_k(const int* __restrict__ dst,
                                              int* __restrict__ deg, int E)
{
    int e = blockIdx.x * TPB + threadIdx.x;
    if (e < E) atomicAdd(&deg[dst[e]], 1);
}

// scan_a: per-1024-block inclusive scan of deg (for row_ptr); plus per-block
// degree-bin histogram (LDS) with per-node local rank; bcnt is bin-major.
__global__ void __launch_bounds__(TPB) scan_a_k(const int* __restrict__ deg, int n,
                                                int* __restrict__ incl,
                                                int* __restrict__ bsum,
                                                int* __restrict__ bcnt, int nb,
                                                int* __restrict__ rank)
{
    __shared__ int ts[TPB];
    __shared__ int lhist[64];
    if (threadIdx.x < 64) lhist[threadIdx.x] = 0;
    const int base = blockIdx.x * 1024;
    int vals[4], s = 0;
#pragma unroll
    for (int j = 0; j < 4; ++j) {
        int i = base + threadIdx.x * 4 + j;
        vals[j] = (i < n) ? deg[i] : 0;
        s += vals[j];
    }
    ts[threadIdx.x] = s;
    __syncthreads();
#pragma unroll
    for (int j = 0; j < 4; ++j) {
        int i = base + threadIdx.x * 4 + j;
        if (i < n) {
            int bin = 63 - min(vals[j], 63);   // descending degree order
            rank[i] = atomicAdd(&lhist[bin], 1);
        }
    }
    for (int off = 1; off < TPB; off <<= 1) {
        int u = (threadIdx.x >= off) ? ts[threadIdx.x - off] : 0;
        __syncthreads();
        ts[threadIdx.x] += u;
        __syncthreads();
    }
    int run = ts[threadIdx.x] - s;
#pragma unroll
    for (int j = 0; j < 4; ++j) {
        run += vals[j];
        int i = base + threadIdx.x * 4 + j;
        if (i < n) incl[i] = run;
    }
    if (threadIdx.x == TPB - 1) bsum[blockIdx.x] = ts[TPB - 1];
    __syncthreads();
    if (threadIdx.x < 64) bcnt[threadIdx.x * nb + blockIdx.x] = lhist[threadIdx.x];
}

// scan_b: exclusive scan of bsum (nb<=256) and of bcnt (64*nb, bin-major).
__global__ void __launch_bounds__(TPB) scan_b_k(int* __restrict__ bsum, int nb,
                                                int* __restrict__ bcnt)
{
    __shared__ int ts[TPB];
    const int t = threadIdx.x;
    int v = (t < nb) ? bsum[t] : 0;
    ts[t] = v;
    __syncthreads();
    for (int off = 1; off < TPB; off <<= 1) {
        int u = (t >= off) ? ts[t - off] : 0;
        __syncthreads();
        ts[t] += u;
        __syncthreads();
    }
    if (t < nb) bsum[t] = ts[t] - v;
    __syncthreads();

    // bcnt exclusive scan: 64*nb elems, C = ceil per thread, contiguous chunks
    const int total = 64 * nb;
    const int C = (total + TPB - 1) / TPB;
    int loc[32];   // C <= 13 for nb=49; allow headroom
    int s = 0;
    for (int j = 0; j < C; ++j) {
        int i = t * C + j;
        loc[j] = (i < total) ? bcnt[i] : 0;
        s += loc[j];
    }
    __syncthreads();
    ts[t] = s;
    __syncthreads();
    for (int off = 1; off < TPB; off <<= 1) {
        int u = (t >= off) ? ts[t - off] : 0;
        __syncthreads();
        ts[t] += u;
        __syncthreads();
    }
    int run = ts[t] - s;
    for (int j = 0; j < C; ++j) {
        int i = t * C + j;
        if (i < total) bcnt[i] = run;
        run += loc[j];
    }
}

// finalize: row_ptr/cursor + perm[pos]=i with pos from scanned bcnt + rank.
__global__ void __launch_bounds__(TPB) finalize_k(const int* __restrict__ incl,
                                                  const int* __restrict__ deg,
                                                  const int* __restrict__ bsum, int n,
                                                  int* __restrict__ row_ptr,
                                                  int* __restrict__ cursor,
                                                  const int* __restrict__ bcnt, int nb,
                                                  const int* __restrict__ rank,
                                                  int* __restrict__ perm)
{
    const int base = blockIdx.x * 1024;
    const int boff = bsum[blockIdx.x];
#pragma unroll
    for (int j = 0; j < 4; ++j) {
        int i = base + threadIdx.x * 4 + j;
        if (i < n) {
            int dg = deg[i];
            int iv = incl[i] + boff;
            row_ptr[i] = iv - dg;
            cursor[i] = iv - dg;
            if (i == n - 1) row_ptr[n] = iv;
            int bin = 63 - min(dg, 63);
            perm[bcnt[bin * nb + blockIdx.x] + rank[i]] = i;
        }
    }
}

__global__ void __launch_bounds__(TPB) scatter_k(
    const int* __restrict__ src, const int* __restrict__ dst,
    const float* __restrict__ ea, int* __restrict__ cursor,
    unsigned* __restrict__ csr_pack, int E)
{
    int e = blockIdx.x * TPB + threadIdx.x;
    if (e >= E) return;
    int pos = atomicAdd(&cursor[dst[e]], 1);
    csr_pack[pos] = ((unsigned)f2bf(ea[e]) << 16) | (unsigned)src[e];
}

// ---- gather attention: 16 lanes/node, degree-sorted perm, packed CSR ----
template <bool BF16OUT>
__global__ void __launch_bounds__(TPB) node_attn_k(
    const unsigned short* __restrict__ q, const unsigned short* __restrict__ kv,
    const float* __restrict__ skip, const float* __restrict__ We,
    const int* __restrict__ row_ptr, const unsigned* __restrict__ csr_pack,
    const int* __restrict__ perm,
    void* __restrict__ outp, int n)
{
    const int slot = blockIdx.x * 16 + (threadIdx.x >> 4);
    if (slot >= n) return;
    const int node = perm[slot];
    const int l16 = threadIdx.x & 15;
    const int c8 = l16 * 8;

    const float C2 = 0.17677669529663687f * 1.44269504088896f; // 1/sqrt(32)*log2e

    float we8[8], qv[8];
    {
        float4 wlo = *(const float4*)(We + c8);
        float4 whi = *(const float4*)(We + c8 + 4);
        we8[0] = wlo.x; we8[1] = wlo.y; we8[2] = wlo.z; we8[3] = wlo.w;
        we8[4] = whi.x; we8[5] = whi.y; we8[6] = whi.z; we8[7] = whi.w;
        ushort8v qu = *(const ushort8v*)(q + (size_t)node * 128 + c8);
#pragma unroll
        for (int i = 0; i < 8; ++i) qv[i] = bf2f((unsigned short)qu[i]) * C2;
    }

    float qwe = 0.f;
#pragma unroll
    for (int i = 0; i < 8; ++i) qwe = fmaf(qv[i], we8[i], qwe);
    qwe += __shfl_xor(qwe, 1);
    qwe += __shfl_xor(qwe, 2);

    const int p0 = row_ptr[node], p1 = row_ptr[node + 1];

    float m = -3.4e38f, l = 0.f, sae = 0.f;
    float acc[8];
#pragma unroll
    for (int i = 0; i < 8; ++i) acc[i] = 0.f;

    for (int j = p0; j < p1; j += 4) {
        const int last = p1 - 1;
        unsigned pr0 = csr_pack[j];
        unsigned pr1 = csr_pack[min(j + 1, last)];
        unsigned pr2 = csr_pack[min(j + 2, last)];
        unsigned pr3 = csr_pack[min(j + 3, last)];
        const unsigned short* b0 = kv + (pr0 & 0xFFFFu) * 256u + c8;
        const unsigned short* b1 = kv + (pr1 & 0xFFFFu) * 256u + c8;
        const unsigned short* b2 = kv + (pr2 & 0xFFFFu) * 256u + c8;
        const unsigned short* b3 = kv + (pr3 & 0xFFFFu) * 256u + c8;
        ushort8v ku0 = *(const ushort8v*)b0;
        ushort8v ku1 = *(const ushort8v*)b1;
        ushort8v ku2 = *(const ushort8v*)b2;
        ushort8v ku3 = *(const ushort8v*)b3;
        ushort8v vu0 = *(const ushort8v*)(b0 + 128);
        ushort8v vu1 = *(const ushort8v*)(b1 + 128);
        ushort8v vu2 = *(const ushort8v*)(b2 + 128);
        ushort8v vu3 = *(const ushort8v*)(b3 + 128);

        float d0 = 0.f, d1 = 0.f, d2 = 0.f, d3 = 0.f;
#pragma unroll
        for (int i = 0; i < 8; ++i) {
            d0 = fmaf(bf2f((unsigned short)ku0[i]), qv[i], d0);
            d1 = fmaf(bf2f((unsigned short)ku1[i]), qv[i], d1);
            d2 = fmaf(bf2f((unsigned short)ku2[i]), qv[i], d2);
            d3 = fmaf(bf2f((unsigned short)ku3[i]), qv[i], d3);
        }
        d0 += __shfl_xor(d0, 1); d0 += __shfl_xor(d0, 2);
        d1 += __shfl_xor(d1, 1); d1 += __shfl_xor(d1, 2);
        d2 += __shfl_xor(d2, 1); d2 += __shfl_xor(d2, 2);
        d3 += __shfl_xor(d3, 1); d3 += __shfl_xor(d3, 2);

        float ea0 = bf2f((unsigned short)(pr0 >> 16));
        float ea1 = bf2f((unsigned short)(pr1 >> 16));
        float ea2 = bf2f((unsigned short)(pr2 >> 16));
        float ea3 = bf2f((unsigned short)(pr3 >> 16));
        float al0 = fmaf(ea0, qwe, d0);
        float al1 = (j + 1 < p1) ? fmaf(ea1, qwe, d1) : -3.4e38f;
        float al2 = (j + 2 < p1) ? fmaf(ea2, qwe, d2) : -3.4e38f;
        float al3 = (j + 3 < p1) ? fmaf(ea3, qwe, d3) : -3.4e38f;

        float mn = fmaxf(m, fmaxf(fmaxf(al0, al1), fmaxf(al2, al3)));
        float sc = exp2_hw(m - mn);
        float pe0 = exp2_hw(al0 - mn), pe1 = exp2_hw(al1 - mn);
        float pe2 = exp2_hw(al2 - mn), pe3 = exp2_hw(al3 - mn);

        l = fmaf(l, sc, (pe0 + pe1) + (pe2 + pe3));
        sae = fmaf(sae, sc, fmaf(pe3, ea3, fmaf(pe2, ea2, fmaf(pe1, ea1, pe0 * ea0))));
#pragma unroll
        for (int i = 0; i < 8; ++i) {
            float mv = fmaf(pe0, bf2f((unsigned short)vu0[i]),
                       fmaf(pe1, bf2f((unsigned short)vu1[i]),
                       fmaf(pe2, bf2f((unsigned short)vu2[i]),
                            pe3 * bf2f((unsigned short)vu3[i]))));
            acc[i] = fmaf(acc[i], sc, mv);
        }
        m = mn;
    }

    float inv = 1.f / (l + 1e-16f);
    float4 sklo = *(const float4*)(skip + (size_t)node * 128 + c8);
    float4 skhi = *(const float4*)(skip + (size_t)node * 128 + c8 + 4);
    float sk[8] = {sklo.x, sklo.y, sklo.z, sklo.w, skhi.x, skhi.y, skhi.z, skhi.w};
    float o[8];
#pragma unroll
    for (int i = 0; i < 8; ++i)
        o[i] = fmaxf(fmaf(fmaf(sae, we8[i], acc[i]), inv, sk[i]), 0.f);

    if (BF16OUT) {
        ushort8v ov;
#pragma unroll
        for (int i = 0; i < 8; ++i) ov[i] = f2bf(o[i]);
        *(ushort8v*)((unsigned short*)outp + (size_t)node * 128 + c8) = ov;
    } else {
        float* op = (float*)outp + (size_t)node * 128 + c8;
        *(float4*)op = make_float4(o[0], o[1], o[2], o[3]);
        *(float4*)(op + 4) = make_float4(o[4], o[5], o[6], o[7]);
    }
}

extern "C" void kernel_launch(void* const* d_in, const int* in_sizes, int n_in,
                              void* d_out, int out_size, void* d_ws, size_t ws_size,
                              hipStream_t stream)
{
    const float* x   = (const float*)d_in[0];
    const int*   ei  = (const int*)d_in[1];
    const float* ea  = (const float*)d_in[2];
    const float* Wq1 = (const float*)d_in[3];  const float* bq1 = (const float*)d_in[4];
    const float* Wk1 = (const float*)d_in[5];  const float* bk1 = (const float*)d_in[6];
    const float* Wv1 = (const float*)d_in[7];  const float* bv1 = (const float*)d_in[8];
    const float* We1 = (const float*)d_in[9];
    const float* Ws1 = (const float*)d_in[10]; const float* bs1 = (const float*)d_in[11];
    const float* Wq2 = (const float*)d_in[12]; const float* bq2 = (const float*)d_in[13];
    const float* Wk2 = (const float*)d_in[14]; const float* bk2 = (const float*)d_in[15];
    const float* Wv2 = (const float*)d_in[16]; const float* bv2 = (const float*)d_in[17];
    const float* We2 = (const float*)d_in[18];
    const float* Ws2 = (const float*)d_in[19]; const float* bs2 = (const float*)d_in[20];

    const int N = in_sizes[0] / 128;
    const int E = in_sizes[1] / 2;
    const int* src = ei;
    const int* dst = ei + E;
    float* outf = (float*)d_out;

    const int nb = (N + 1023) / 1024;

    // workspace layout
    unsigned short* q  = (unsigned short*)d_ws;          // N*128 bf16
    unsigned short* kv = q + (size_t)N * 128;            // N*256 bf16 (k|v)
    float*          s  = (float*)(kv + (size_t)N * 256); // N*128 f32 skip
    unsigned short* xb = (unsigned short*)(s + (size_t)N * 128); // bf16 x / h
    unsigned short* pk = xb + (size_t)N * 128;           // 131072 (both layers)
    int*   row_ptr = (int*)(pk + 131072);                // N+1
    int*   deg     = row_ptr + (N + 1);                  // N  (memset)
    int*   incl    = deg + N;                            // N
    int*   cursor  = incl + N;                           // N
    int*   rank    = cursor + N;                         // N
    int*   bsum    = rank + N;                           // 256
    int*   bcnt    = bsum + 256;                         // 64*nb
    int*   perm    = bcnt + 64 * nb;                     // N
    unsigned* csr_pack = (unsigned*)(perm + N);          // E

    const int gE   = (E + TPB - 1) / TPB;
    const int gN16 = (N + 15) / 16;
    const int n4   = N * 128 / 4;
    const int gPC  = 512 + (n4 + TPB - 1) / TPB;
    const int gG   = (N + 127) / 128;
    const dim3 gGd(gG, 4);

    // ---- CSR build + degree sort (shared by both layers) ----
    hipMemsetAsync(deg, 0, (size_t)N * sizeof(int), stream);
    hist_k<<<gE, TPB, 0, stream>>>(dst, deg, E);
    scan_a_k<<<nb, TPB, 0, stream>>>(deg, N, incl, bsum, bcnt, nb, rank);
    scan_b_k<<<1, TPB, 0, stream>>>(bsum, nb, bcnt);
    finalize_k<<<nb, TPB, 0, stream>>>(incl, deg, bsum, N, row_ptr, cursor,
                                       bcnt, nb, rank, perm);
    scatter_k<<<gE, TPB, 0, stream>>>(src, dst, ea, cursor, csr_pack, E);

    // ---- weight prepack (both layers) + x convert ----
    prep_cvt_k<<<gPC, TPB, 0, stream>>>(Wq1, Wk1, Wv1, Ws1, Wq2, Wk2, Wv2, Ws2,
                                        pk, x, xb, n4);

    // ---- layer 1 ----
    gemm_mfma_k<<<gGd, TPB, 0, stream>>>(xb, N, pk, bq1, bk1, bv1, bs1, q, kv, s);
    node_attn_k<true><<<gN16, TPB, 0, stream>>>(q, kv, s, We1, row_ptr, csr_pack,
                                                perm, xb, N);
    // ---- layer 2 ----
    gemm_mfma_k<<<gGd, TPB, 0, stream>>>(xb, N, pk + 65536, bq2, bk2, bv2, bs2,
                                         q, kv, s);
    node_attn_k<false><<<gN16, TPB, 0, stream>>>(q, kv, s, We2, row_ptr, csr_pack,
                                                 perm, outf, N);
}

// Round 12
// 303.018 us; speedup vs baseline: 1.9606x; 1.0715x over previous
//
#include <hip/hip_runtime.h>

// TransformerConv x2 on MI355X — 32x32 MFMA GEMM + degree-sorted 16-lane
// gather attention (8-edge unroll), interleaved kv, 4-B CSR, bf16 skip.
// N=50000, E=800000, H=4, C=32, D=128.

#define TPB 256

typedef __attribute__((ext_vector_type(8))) short short8v;
typedef __attribute__((ext_vector_type(8))) unsigned short ushort8v;
typedef __attribute__((ext_vector_type(16))) float f32x16;

__device__ __forceinline__ unsigned short f2bf(float f) {
    unsigned u = __float_as_uint(f);
    u = (u + 0x7FFFu + ((u >> 16) & 1u)) >> 16;
    return (unsigned short)u;
}
__device__ __forceinline__ float bf2f(unsigned short s) {
    return __uint_as_float((unsigned)s << 16);
}
__device__ __forceinline__ float exp2_hw(float x) {
    float r;
    asm("v_exp_f32 %0, %1" : "=v"(r) : "v"(x));
    return r;
}

// ---- fused: weight prepack (32x32 B-fragments) + x fp32->bf16 convert ----
__global__ void __launch_bounds__(TPB) prep_cvt_k(
    const float* __restrict__ Wq1, const float* __restrict__ Wk1,
    const float* __restrict__ Wv1, const float* __restrict__ Ws1,
    const float* __restrict__ Wq2, const float* __restrict__ Wk2,
    const float* __restrict__ Wv2, const float* __restrict__ Ws2,
    unsigned short* __restrict__ pack,
    const float* __restrict__ x, unsigned short* __restrict__ xb, int n4)
{
    if (blockIdx.x < 512) {
        int i = blockIdx.x * TPB + threadIdx.x;   // 131072 total
        int j = i & 7, lane = (i >> 3) & 63, t = (i >> 9) & 7, nc = (i >> 12) & 3, g = (i >> 14) & 7;
        const float* Wt[8] = {Wq1, Wk1, Wv1, Ws1, Wq2, Wk2, Wv2, Ws2};
        const float* W = Wt[g];
        int kk = t * 16 + (lane >> 5) * 8 + j;
        int nn = nc * 32 + (lane & 31);
        pack[i] = f2bf(W[kk * 128 + nn]);
    } else {
        int i = (blockIdx.x - 512) * TPB + threadIdx.x;
        if (i >= n4) return;
        float4 v = *(const float4*)(x + (size_t)i * 4);
        ushort4 o;
        o.x = f2bf(v.x); o.y = f2bf(v.y); o.z = f2bf(v.z); o.w = f2bf(v.w);
        *(ushort4*)(xb + (size_t)i * 4) = o;
    }
}

// ---- MFMA GEMM (32x32x16): g=blockIdx.y: 0->q, 1->kv k-half, 2->kv v-half,
//      3->skip (bf16) ----
__global__ void __launch_bounds__(TPB) gemm_mfma_k(
    const unsigned short* __restrict__ A, int M,
    const unsigned short* __restrict__ pack,
    const float* __restrict__ bq, const float* __restrict__ bk,
    const float* __restrict__ bv, const float* __restrict__ bs,
    unsigned short* __restrict__ oq, unsigned short* __restrict__ okv,
    unsigned short* __restrict__ os)
{
    const int g = blockIdx.y;
    const int row0 = blockIdx.x * 128;
    const int wv = threadIdx.x >> 6;
    const int lane = threadIdx.x & 63;
    const int rbase = row0 + wv * 32;
    const int arow = rbase + (lane & 31);
    const int kh = (lane >> 5) * 8;

    const short8v z8 = {0, 0, 0, 0, 0, 0, 0, 0};
    short8v a[8];
    if (arow < M) {
        const unsigned short* Ap = A + (size_t)arow * 128 + kh;
#pragma unroll
        for (int t = 0; t < 8; ++t) a[t] = *(const short8v*)(Ap + t * 16);
    } else {
#pragma unroll
        for (int t = 0; t < 8; ++t) a[t] = z8;
    }

    f32x16 acc[4];
#pragma unroll
    for (int nc = 0; nc < 4; ++nc)
#pragma unroll
        for (int r = 0; r < 16; ++r) acc[nc][r] = 0.f;

    const unsigned short* bp = pack + (size_t)g * 16384;
#pragma unroll
    for (int nc = 0; nc < 4; ++nc) {
#pragma unroll
        for (int t = 0; t < 8; ++t) {
            short8v b = *(const short8v*)(bp + (nc * 8 + t) * 512 + lane * 8);
            acc[nc] = __builtin_amdgcn_mfma_f32_32x32x16_bf16(a[t], b, acc[nc], 0, 0, 0);
        }
    }

    const float* bias = g == 0 ? bq : (g == 1 ? bk : (g == 2 ? bv : bs));
    const int col = lane & 31;
    const int rb2 = rbase + 4 * (lane >> 5);
    unsigned short* out = g == 0 ? oq : (g == 3 ? os : okv);
    const int stride = (g == 1 || g == 2) ? 256 : 128;
    const int goff = g == 2 ? 128 : 0;
#pragma unroll
    for (int nc = 0; nc < 4; ++nc) {
        float bb = bias[nc * 32 + col];
#pragma unroll
        for (int r = 0; r < 16; ++r) {
            int row = rb2 + (r & 3) + 8 * (r >> 2);
            if (row < M)
                out[(size_t)row * stride + goff + nc * 32 + col] = f2bf(acc[nc][r] + bb);
        }
    }
}

// ---------------- CSR build + two-level degree counting-sort ----------------
__global__ void __launch_bounds__(TPB) hist_k(const int* __restrict__ dst,
                                              int* __restrict__ deg, int E)
{
    int e = blockIdx.x * TPB + threadIdx.x;
    if (e < E) atomicAdd(&deg[dst[e]], 1);
}

__global__ void __launch_bounds__(TPB) scan_a_k(const int* __restrict__ deg, int n,
                                                int* __restrict__ incl,
                                                int* __restrict__ bsum,
                                                int* __restrict__ bcnt, int nb,
                                                int* __restrict__ rank)
{
    __shared__ int ts[TPB];
    __shared__ int lhist[64];
    if (threadIdx.x < 64) lhist[threadIdx.x] = 0;
    const int base = blockIdx.x * 1024;
    int vals[4], s = 0;
#pragma unroll
    for (int j = 0; j < 4; ++j) {
        int i = base + threadIdx.x * 4 + j;
        vals[j] = (i < n) ? deg[i] : 0;
        s += vals[j];
    }
    ts[threadIdx.x] = s;
    __syncthreads();
#pragma unroll
    for (int j = 0; j < 4; ++j) {
        int i = base + threadIdx.x * 4 + j;
        if (i < n) {
            int bin = 63 - min(vals[j], 63);   // descending degree order
            rank[i] = atomicAdd(&lhist[bin], 1);
        }
    }
    for (int off = 1; off < TPB; off <<= 1) {
        int u = (threadIdx.x >= off) ? ts[threadIdx.x - off] : 0;
        __syncthreads();
        ts[threadIdx.x] += u;
        __syncthreads();
    }
    int run = ts[threadIdx.x] - s;
#pragma unroll
    for (int j = 0; j < 4; ++j) {
        run += vals[j];
        int i = base + threadIdx.x * 4 + j;
        if (i < n) incl[i] = run;
    }
    if (threadIdx.x == TPB - 1) bsum[blockIdx.x] = ts[TPB - 1];
    __syncthreads();
    if (threadIdx.x < 64) bcnt[threadIdx.x * nb + blockIdx.x] = lhist[threadIdx.x];
}

__global__ void __launch_bounds__(TPB) scan_b_k(int* __restrict__ bsum, int nb,
                                                int* __restrict__ bcnt)
{
    __shared__ int ts[TPB];
    const int t = threadIdx.x;
    int v = (t < nb) ? bsum[t] : 0;
    ts[t] = v;
    __syncthreads();
    for (int off = 1; off < TPB; off <<= 1) {
        int u = (t >= off) ? ts[t - off] : 0;
        __syncthreads();
        ts[t] += u;
        __syncthreads();
    }
    if (t < nb) bsum[t] = ts[t] - v;
    __syncthreads();

    const int total = 64 * nb;
    const int C = (total + TPB - 1) / TPB;
    int loc[32];
    int s = 0;
    for (int j = 0; j < C; ++j) {
        int i = t * C + j;
        loc[j] = (i < total) ? bcnt[i] : 0;
        s += loc[j];
    }
    __syncthreads();
    ts[t] = s;
    __syncthreads();
    for (int off = 1; off < TPB; off <<= 1) {
        int u = (t >= off) ? ts[t - off] : 0;
        __syncthreads();
        ts[t] += u;
        __syncthreads();
    }
    int run = ts[t] - s;
    for (int j = 0; j < C; ++j) {
        int i = t * C + j;
        if (i < total) bcnt[i] = run;
        run += loc[j];
    }
}

__global__ void __launch_bounds__(TPB) finalize_k(const int* __restrict__ incl,
                                                  const int* __restrict__ deg,
                                                  const int* __restrict__ bsum, int n,
                                                  int* __restrict__ row_ptr,
                                                  int* __restrict__ cursor,
                                                  const int* __restrict__ bcnt, int nb,
                                                  const int* __restrict__ rank,
                                                  int* __restrict__ perm)
{
    const int base = blockIdx.x * 1024;
    const int boff = bsum[blockIdx.x];
#pragma unroll
    for (int j = 0; j < 4; ++j) {
        int i = base + threadIdx.x * 4 + j;
        if (i < n) {
            int dg = deg[i];
            int iv = incl[i] + boff;
            row_ptr[i] = iv - dg;
            cursor[i] = iv - dg;
            if (i == n - 1) row_ptr[n] = iv;
            int bin = 63 - min(dg, 63);
            perm[bcnt[bin * nb + blockIdx.x] + rank[i]] = i;
        }
    }
}

__global__ void __launch_bounds__(TPB) scatter_k(
    const int* __restrict__ src, const int* __restrict__ dst,
    const float* __restrict__ ea, int* __restrict__ cursor,
    unsigned* __restrict__ csr_pack, int E)
{
    int e = blockIdx.x * TPB + threadIdx.x;
    if (e >= E) return;
    int pos = atomicAdd(&cursor[dst[e]], 1);
    csr_pack[pos] = ((unsigned)f2bf(ea[e]) << 16) | (unsigned)src[e];
}

// ---- gather attention: 16 lanes/node, 8-edge unroll, degree-sorted perm ----
template <bool BF16OUT>
__global__ void __launch_bounds__(TPB) node_attn_k(
    const unsigned short* __restrict__ q, const unsigned short* __restrict__ kv,
    const unsigned short* __restrict__ skip, const float* __restrict__ We,
    const int* __restrict__ row_ptr, const unsigned* __restrict__ csr_pack,
    const int* __restrict__ perm,
    void* __restrict__ outp, int n)
{
    const int slot = blockIdx.x * 16 + (threadIdx.x >> 4);
    if (slot >= n) return;
    const int node = perm[slot];
    const int l16 = threadIdx.x & 15;
    const int c8 = l16 * 8;

    const float C2 = 0.17677669529663687f * 1.44269504088896f; // 1/sqrt(32)*log2e

    float we8[8], qv[8];
    {
        float4 wlo = *(const float4*)(We + c8);
        float4 whi = *(const float4*)(We + c8 + 4);
        we8[0] = wlo.x; we8[1] = wlo.y; we8[2] = wlo.z; we8[3] = wlo.w;
        we8[4] = whi.x; we8[5] = whi.y; we8[6] = whi.z; we8[7] = whi.w;
        ushort8v qu = *(const ushort8v*)(q + (size_t)node * 128 + c8);
#pragma unroll
        for (int i = 0; i < 8; ++i) qv[i] = bf2f((unsigned short)qu[i]) * C2;
    }

    float qwe = 0.f;
#pragma unroll
    for (int i = 0; i < 8; ++i) qwe = fmaf(qv[i], we8[i], qwe);
    qwe += __shfl_xor(qwe, 1);
    qwe += __shfl_xor(qwe, 2);

    const int p0 = row_ptr[node], p1 = row_ptr[node + 1];

    float m = -3.4e38f, l = 0.f, sae = 0.f;
    float acc[8];
#pragma unroll
    for (int i = 0; i < 8; ++i) acc[i] = 0.f;

    for (int j = p0; j < p1; j += 8) {
        const int last = p1 - 1;
        unsigned pr[8];
#pragma unroll
        for (int t = 0; t < 8; ++t) pr[t] = csr_pack[min(j + t, last)];

        ushort8v ku[8], vu[8];
#pragma unroll
        for (int t = 0; t < 8; ++t) {
            const unsigned short* b = kv + (pr[t] & 0xFFFFu) * 256u + c8;
            ku[t] = *(const ushort8v*)b;
            vu[t] = *(const ushort8v*)(b + 128);
        }

        float d[8];
#pragma unroll
        for (int t = 0; t < 8; ++t) {
            float dd = 0.f;
#pragma unroll
            for (int i = 0; i < 8; ++i)
                dd = fmaf(bf2f((unsigned short)ku[t][i]), qv[i], dd);
            dd += __shfl_xor(dd, 1);
            dd += __shfl_xor(dd, 2);
            d[t] = dd;
        }

        float eav[8], al[8];
#pragma unroll
        for (int t = 0; t < 8; ++t) {
            eav[t] = bf2f((unsigned short)(pr[t] >> 16));
            al[t] = (t == 0 || j + t < p1) ? fmaf(eav[t], qwe, d[t]) : -3.4e38f;
        }

        float mn = m;
#pragma unroll
        for (int t = 0; t < 8; ++t) mn = fmaxf(mn, al[t]);
        float sc = exp2_hw(m - mn);
        float pe[8];
#pragma unroll
        for (int t = 0; t < 8; ++t) pe[t] = exp2_hw(al[t] - mn);

        float ls = 0.f, ss = 0.f;
#pragma unroll
        for (int t = 0; t < 8; ++t) { ls += pe[t]; ss = fmaf(pe[t], eav[t], ss); }
        l = fmaf(l, sc, ls);
        sae = fmaf(sae, sc, ss);
#pragma unroll
        for (int i = 0; i < 8; ++i) {
            float mv = 0.f;
#pragma unroll
            for (int t = 0; t < 8; ++t)
                mv = fmaf(pe[t], bf2f((unsigned short)vu[t][i]), mv);
            acc[i] = fmaf(acc[i], sc, mv);
        }
        m = mn;
    }

    float inv = 1.f / (l + 1e-16f);
    ushort8v sku = *(const ushort8v*)(skip + (size_t)node * 128 + c8);
    float o[8];
#pragma unroll
    for (int i = 0; i < 8; ++i)
        o[i] = fmaxf(fmaf(fmaf(sae, we8[i], acc[i]), inv,
                          bf2f((unsigned short)sku[i])), 0.f);

    if (BF16OUT) {
        ushort8v ov;
#pragma unroll
        for (int i = 0; i < 8; ++i) ov[i] = f2bf(o[i]);
        *(ushort8v*)((unsigned short*)outp + (size_t)node * 128 + c8) = ov;
    } else {
        float* op = (float*)outp + (size_t)node * 128 + c8;
        *(float4*)op = make_float4(o[0], o[1], o[2], o[3]);
        *(float4*)(op + 4) = make_float4(o[4], o[5], o[6], o[7]);
    }
}

extern "C" void kernel_launch(void* const* d_in, const int* in_sizes, int n_in,
                              void* d_out, int out_size, void* d_ws, size_t ws_size,
                              hipStream_t stream)
{
    const float* x   = (const float*)d_in[0];
    const int*   ei  = (const int*)d_in[1];
    const float* ea  = (const float*)d_in[2];
    const float* Wq1 = (const float*)d_in[3];  const float* bq1 = (const float*)d_in[4];
    const float* Wk1 = (const float*)d_in[5];  const float* bk1 = (const float*)d_in[6];
    const float* Wv1 = (const float*)d_in[7];  const float* bv1 = (const float*)d_in[8];
    const float* We1 = (const float*)d_in[9];
    const float* Ws1 = (const float*)d_in[10]; const float* bs1 = (const float*)d_in[11];
    const float* Wq2 = (const float*)d_in[12]; const float* bq2 = (const float*)d_in[13];
    const float* Wk2 = (const float*)d_in[14]; const float* bk2 = (const float*)d_in[15];
    const float* Wv2 = (const float*)d_in[16]; const float* bv2 = (const float*)d_in[17];
    const float* We2 = (const float*)d_in[18];
    const float* Ws2 = (const float*)d_in[19]; const float* bs2 = (const float*)d_in[20];

    const int N = in_sizes[0] / 128;
    const int E = in_sizes[1] / 2;
    const int* src = ei;
    const int* dst = ei + E;
    float* outf = (float*)d_out;

    const int nb = (N + 1023) / 1024;

    // workspace layout
    unsigned short* q  = (unsigned short*)d_ws;          // N*128 bf16
    unsigned short* kv = q + (size_t)N * 128;            // N*256 bf16 (k|v)
    unsigned short* s  = kv + (size_t)N * 256;           // N*128 bf16 skip
    unsigned short* xb = s + (size_t)N * 128;            // bf16 x / h
    unsigned short* pk = xb + (size_t)N * 128;           // 131072 (both layers)
    int*   row_ptr = (int*)(pk + 131072);                // N+1
    int*   deg     = row_ptr + (N + 1);                  // N  (memset)
    int*   incl    = deg + N;                            // N
    int*   cursor  = incl + N;                           // N
    int*   rank    = cursor + N;                         // N
    int*   bsum    = rank + N;                           // 256
    int*   bcnt    = bsum + 256;                         // 64*nb
    int*   perm    = bcnt + 64 * nb;                     // N
    unsigned* csr_pack = (unsigned*)(perm + N);          // E

    const int gE   = (E + TPB - 1) / TPB;
    const int gN16 = (N + 15) / 16;
    const int n4   = N * 128 / 4;
    const int gPC  = 512 + (n4 + TPB - 1) / TPB;
    const int gG   = (N + 127) / 128;
    const dim3 gGd(gG, 4);

    // ---- CSR build + degree sort (shared by both layers) ----
    hipMemsetAsync(deg, 0, (size_t)N * sizeof(int), stream);
    hist_k<<<gE, TPB, 0, stream>>>(dst, deg, E);
    scan_a_k<<<nb, TPB, 0, stream>>>(deg, N, incl, bsum, bcnt, nb, rank);
    scan_b_k<<<1, TPB, 0, stream>>>(bsum, nb, bcnt);
    finalize_k<<<nb, TPB, 0, stream>>>(incl, deg, bsum, N, row_ptr, cursor,
                                       bcnt, nb, rank, perm);
    scatter_k<<<gE, TPB, 0, stream>>>(src, dst, ea, cursor, csr_pack, E);

    // ---- weight prepack (both layers) + x convert ----
    prep_cvt_k<<<gPC, TPB, 0, stream>>>(Wq1, Wk1, Wv1, Ws1, Wq2, Wk2, Wv2, Ws2,
                                        pk, x, xb, n4);

    // ---- layer 1 ----
    gemm_mfma_k<<<gGd, TPB, 0, stream>>>(xb, N, pk, bq1, bk1, bv1, bs1, q, kv, s);
    node_attn_k<true><<<gN16, TPB, 0, stream>>>(q, kv, s, We1, row_ptr, csr_pack,
                                                perm, xb, N);
    // ---- layer 2 ----
    gemm_mfma_k<<<gGd, TPB, 0, stream>>>(xb, N, pk + 65536, bq2, bk2, bv2, bs2,
                                         q, kv, s);
    node_attn_k<false><<<gN16, TPB, 0, stream>>>(q, kv, s, We2, row_ptr, csr_pack,
                                                 perm, outf, N);
}

// Round 13
// 295.475 us; speedup vs baseline: 2.0106x; 1.0255x over previous
//
#include <hip/hip_runtime.h>

// TransformerConv x2 on MI355X — fused-launch 32x32 MFMA GEMM (XCD-chunked) +
// degree-sorted 16-lane gather attention, interleaved kv, 4-B CSR, bf16 skip.
// N=50000, E=800000, H=4, C=32, D=128.

#define TPB 256

typedef __attribute__((ext_vector_type(8))) short short8v;
typedef __attribute__((ext_vector_type(8))) unsigned short ushort8v;
typedef __attribute__((ext_vector_type(16))) float f32x16;

__device__ __forceinline__ unsigned short f2bf(float f) {
    unsigned u = __float_as_uint(f);
    u = (u + 0x7FFFu + ((u >> 16) & 1u)) >> 16;
    return (unsigned short)u;
}
__device__ __forceinline__ float bf2f(unsigned short s) {
    return __uint_as_float((unsigned)s << 16);
}
__device__ __forceinline__ float exp2_hw(float x) {
    float r;
    asm("v_exp_f32 %0, %1" : "=v"(r) : "v"(x));
    return r;
}

// ---- GEMM body (32x32x16), XCD-chunked slot mapping ----
// slot -> (row_tile, g): x = slot%8, j = slot/8, idx = x*pxi + j;
// idx < nrt*4; rt = idx>>2, g = idx&3. Consecutive idx on one XCD ->
// all 4 g-variants of a row tile fill the same XCD's L2 (A reused 4x).
__device__ __forceinline__ void gemm_body(
    int slot, int pxi, int nrt,
    const unsigned short* __restrict__ A, int M,
    const unsigned short* __restrict__ pack,
    const float* __restrict__ bq, const float* __restrict__ bk,
    const float* __restrict__ bv, const float* __restrict__ bs,
    unsigned short* __restrict__ oq, unsigned short* __restrict__ okv,
    unsigned short* __restrict__ os)
{
    const int x = slot & 7, jj = slot >> 3;
    const int idx = x * pxi + jj;
    if (idx >= nrt * 4) return;
    const int g = idx & 3;
    const int row0 = (idx >> 2) * 128;

    const int wv = threadIdx.x >> 6;
    const int lane = threadIdx.x & 63;
    const int rbase = row0 + wv * 32;
    const int arow = rbase + (lane & 31);
    const int kh = (lane >> 5) * 8;

    const short8v z8 = {0, 0, 0, 0, 0, 0, 0, 0};
    short8v a[8];
    if (arow < M) {
        const unsigned short* Ap = A + (size_t)arow * 128 + kh;
#pragma unroll
        for (int t = 0; t < 8; ++t) a[t] = *(const short8v*)(Ap + t * 16);
    } else {
#pragma unroll
        for (int t = 0; t < 8; ++t) a[t] = z8;
    }

    f32x16 acc[4];
#pragma unroll
    for (int nc = 0; nc < 4; ++nc)
#pragma unroll
        for (int r = 0; r < 16; ++r) acc[nc][r] = 0.f;

    const unsigned short* bp = pack + (size_t)g * 16384;
#pragma unroll
    for (int nc = 0; nc < 4; ++nc) {
#pragma unroll
        for (int t = 0; t < 8; ++t) {
            short8v b = *(const short8v*)(bp + (nc * 8 + t) * 512 + lane * 8);
            acc[nc] = __builtin_amdgcn_mfma_f32_32x32x16_bf16(a[t], b, acc[nc], 0, 0, 0);
        }
    }

    const float* bias = g == 0 ? bq : (g == 1 ? bk : (g == 2 ? bv : bs));
    const int col = lane & 31;
    const int rb2 = rbase + 4 * (lane >> 5);
    unsigned short* out = g == 0 ? oq : (g == 3 ? os : okv);
    const int stride = (g == 1 || g == 2) ? 256 : 128;
    const int goff = g == 2 ? 128 : 0;
#pragma unroll
    for (int nc = 0; nc < 4; ++nc) {
        float bb = bias[nc * 32 + col];
#pragma unroll
        for (int r = 0; r < 16; ++r) {
            int row = rb2 + (r & 3) + 8 * (r >> 2);
            if (row < M)
                out[(size_t)row * stride + goff + nc * 32 + col] = f2bf(acc[nc][r] + bb);
        }
    }
}

// ---- fused: edge histogram + weight prepack + x fp32->bf16 convert ----
__global__ void __launch_bounds__(TPB) hist_prep_cvt_k(
    const int* __restrict__ dst, int* __restrict__ deg, int E, int gE,
    const float* __restrict__ Wq1, const float* __restrict__ Wk1,
    const float* __restrict__ Wv1, const float* __restrict__ Ws1,
    const float* __restrict__ Wq2, const float* __restrict__ Wk2,
    const float* __restrict__ Wv2, const float* __restrict__ Ws2,
    unsigned short* __restrict__ pack,
    const float* __restrict__ x, unsigned short* __restrict__ xb, int n4)
{
    if (blockIdx.x < (unsigned)gE) {
        int e = blockIdx.x * TPB + threadIdx.x;
        if (e < E) atomicAdd(&deg[dst[e]], 1);
    } else if (blockIdx.x < (unsigned)(gE + 512)) {
        int i = (blockIdx.x - gE) * TPB + threadIdx.x;   // 131072 total
        int j = i & 7, lane = (i >> 3) & 63, t = (i >> 9) & 7, nc = (i >> 12) & 3, g = (i >> 14) & 7;
        const float* Wt[8] = {Wq1, Wk1, Wv1, Ws1, Wq2, Wk2, Wv2, Ws2};
        const float* W = Wt[g];
        int kk = t * 16 + (lane >> 5) * 8 + j;
        int nn = nc * 32 + (lane & 31);
        pack[i] = f2bf(W[kk * 128 + nn]);
    } else {
        int i = (blockIdx.x - gE - 512) * TPB + threadIdx.x;
        if (i >= n4) return;
        float4 v = *(const float4*)(x + (size_t)i * 4);
        ushort4 o;
        o.x = f2bf(v.x); o.y = f2bf(v.y); o.z = f2bf(v.z); o.w = f2bf(v.w);
        *(ushort4*)(xb + (size_t)i * 4) = o;
    }
}

// ---------------- CSR scan chain (unchanged from R12) ----------------
__global__ void __launch_bounds__(TPB) scan_a_k(const int* __restrict__ deg, int n,
                                                int* __restrict__ incl,
                                                int* __restrict__ bsum,
                                                int* __restrict__ bcnt, int nb,
                                                int* __restrict__ rank)
{
    __shared__ int ts[TPB];
    __shared__ int lhist[64];
    if (threadIdx.x < 64) lhist[threadIdx.x] = 0;
    const int base = blockIdx.x * 1024;
    int vals[4], s = 0;
#pragma unroll
    for (int j = 0; j < 4; ++j) {
        int i = base + threadIdx.x * 4 + j;
        vals[j] = (i < n) ? deg[i] : 0;
        s += vals[j];
    }
    ts[threadIdx.x] = s;
    __syncthreads();
#pragma unroll
    for (int j = 0; j < 4; ++j) {
        int i = base + threadIdx.x * 4 + j;
        if (i < n) {
            int bin = 63 - min(vals[j], 63);   // descending degree order
            rank[i] = atomicAdd(&lhist[bin], 1);
        }
    }
    for (int off = 1; off < TPB; off <<= 1) {
        int u = (threadIdx.x >= off) ? ts[threadIdx.x - off] : 0;
        __syncthreads();
        ts[threadIdx.x] += u;
        __syncthreads();
    }
    int run = ts[threadIdx.x] - s;
#pragma unroll
    for (int j = 0; j < 4; ++j) {
        run += vals[j];
        int i = base + threadIdx.x * 4 + j;
        if (i < n) incl[i] = run;
    }
    if (threadIdx.x == TPB - 1) bsum[blockIdx.x] = ts[TPB - 1];
    __syncthreads();
    if (threadIdx.x < 64) bcnt[threadIdx.x * nb + blockIdx.x] = lhist[threadIdx.x];
}

__global__ void __launch_bounds__(TPB) scan_b_k(int* __restrict__ bsum, int nb,
                                                int* __restrict__ bcnt)
{
    __shared__ int ts[TPB];
    const int t = threadIdx.x;
    int v = (t < nb) ? bsum[t] : 0;
    ts[t] = v;
    __syncthreads();
    for (int off = 1; off < TPB; off <<= 1) {
        int u = (t >= off) ? ts[t - off] : 0;
        __syncthreads();
        ts[t] += u;
        __syncthreads();
    }
    if (t < nb) bsum[t] = ts[t] - v;
    __syncthreads();

    const int total = 64 * nb;
    const int C = (total + TPB - 1) / TPB;
    int loc[32];
    int s = 0;
    for (int j = 0; j < C; ++j) {
        int i = t * C + j;
        loc[j] = (i < total) ? bcnt[i] : 0;
        s += loc[j];
    }
    __syncthreads();
    ts[t] = s;
    __syncthreads();
    for (int off = 1; off < TPB; off <<= 1) {
        int u = (t >= off) ? ts[t - off] : 0;
        __syncthreads();
        ts[t] += u;
        __syncthreads();
    }
    int run = ts[t] - s;
    for (int j = 0; j < C; ++j) {
        int i = t * C + j;
        if (i < total) bcnt[i] = run;
        run += loc[j];
    }
}

__global__ void __launch_bounds__(TPB) finalize_k(const int* __restrict__ incl,
                                                  const int* __restrict__ deg,
                                                  const int* __restrict__ bsum, int n,
                                                  int* __restrict__ row_ptr,
                                                  int* __restrict__ cursor,
                                                  const int* __restrict__ bcnt, int nb,
                                                  const int* __restrict__ rank,
                                                  int* __restrict__ perm)
{
    const int base = blockIdx.x * 1024;
    const int boff = bsum[blockIdx.x];
#pragma unroll
    for (int j = 0; j < 4; ++j) {
        int i = base + threadIdx.x * 4 + j;
        if (i < n) {
            int dg = deg[i];
            int iv = incl[i] + boff;
            row_ptr[i] = iv - dg;
            cursor[i] = iv - dg;
            if (i == n - 1) row_ptr[n] = iv;
            int bin = 63 - min(dg, 63);
            perm[bcnt[bin * nb + blockIdx.x] + rank[i]] = i;
        }
    }
}

// ---- fused: CSR scatter + layer-1 GEMM (independent after finalize) ----
__global__ void __launch_bounds__(TPB) scatter_gemm_k(
    const int* __restrict__ src, const int* __restrict__ dst,
    const float* __restrict__ ea, int* __restrict__ cursor,
    unsigned* __restrict__ csr_pack, int E, int gE,
    int pxi, int nrt,
    const unsigned short* __restrict__ A, int M,
    const unsigned short* __restrict__ pack,
    const float* __restrict__ bq, const float* __restrict__ bk,
    const float* __restrict__ bv, const float* __restrict__ bs,
    unsigned short* __restrict__ oq, unsigned short* __restrict__ okv,
    unsigned short* __restrict__ os)
{
    if (blockIdx.x < (unsigned)gE) {
        int e = blockIdx.x * TPB + threadIdx.x;
        if (e >= E) return;
        int pos = atomicAdd(&cursor[dst[e]], 1);
        csr_pack[pos] = ((unsigned)f2bf(ea[e]) << 16) | (unsigned)src[e];
    } else {
        gemm_body(blockIdx.x - gE, pxi, nrt, A, M, pack, bq, bk, bv, bs, oq, okv, os);
    }
}

__global__ void __launch_bounds__(TPB) gemm_k(
    int pxi, int nrt,
    const unsigned short* __restrict__ A, int M,
    const unsigned short* __restrict__ pack,
    const float* __restrict__ bq, const float* __restrict__ bk,
    const float* __restrict__ bv, const float* __restrict__ bs,
    unsigned short* __restrict__ oq, unsigned short* __restrict__ okv,
    unsigned short* __restrict__ os)
{
    gemm_body(blockIdx.x, pxi, nrt, A, M, pack, bq, bk, bv, bs, oq, okv, os);
}

// ---- gather attention: 16 lanes/node, 8-edge unroll, degree-sorted perm ----
template <bool BF16OUT>
__global__ void __launch_bounds__(TPB) node_attn_k(
    const unsigned short* __restrict__ q, const unsigned short* __restrict__ kv,
    const unsigned short* __restrict__ skip, const float* __restrict__ We,
    const int* __restrict__ row_ptr, const unsigned* __restrict__ csr_pack,
    const int* __restrict__ perm,
    void* __restrict__ outp, int n)
{
    const int slot = blockIdx.x * 16 + (threadIdx.x >> 4);
    if (slot >= n) return;
    const int node = perm[slot];
    const int l16 = threadIdx.x & 15;
    const int c8 = l16 * 8;

    const float C2 = 0.17677669529663687f * 1.44269504088896f; // 1/sqrt(32)*log2e

    float we8[8], qv[8];
    {
        float4 wlo = *(const float4*)(We + c8);
        float4 whi = *(const float4*)(We + c8 + 4);
        we8[0] = wlo.x; we8[1] = wlo.y; we8[2] = wlo.z; we8[3] = wlo.w;
        we8[4] = whi.x; we8[5] = whi.y; we8[6] = whi.z; we8[7] = whi.w;
        ushort8v qu = *(const ushort8v*)(q + (size_t)node * 128 + c8);
#pragma unroll
        for (int i = 0; i < 8; ++i) qv[i] = bf2f((unsigned short)qu[i]) * C2;
    }

    float qwe = 0.f;
#pragma unroll
    for (int i = 0; i < 8; ++i) qwe = fmaf(qv[i], we8[i], qwe);
    qwe += __shfl_xor(qwe, 1);
    qwe += __shfl_xor(qwe, 2);

    const int p0 = row_ptr[node], p1 = row_ptr[node + 1];

    float m = -3.4e38f, l = 0.f, sae = 0.f;
    float acc[8];
#pragma unroll
    for (int i = 0; i < 8; ++i) acc[i] = 0.f;

    for (int j = p0; j < p1; j += 8) {
        const int last = p1 - 1;
        unsigned pr[8];
#pragma unroll
        for (int t = 0; t < 8; ++t) pr[t] = csr_pack[min(j + t, last)];

        ushort8v ku[8], vu[8];
#pragma unroll
        for (int t = 0; t < 8; ++t) {
            const unsigned short* b = kv + (pr[t] & 0xFFFFu) * 256u + c8;
            ku[t] = *(const ushort8v*)b;
            vu[t] = *(const ushort8v*)(b + 128);
        }

        float d[8];
#pragma unroll
        for (int t = 0; t < 8; ++t) {
            float dd = 0.f;
#pragma unroll
            for (int i = 0; i < 8; ++i)
                dd = fmaf(bf2f((unsigned short)ku[t][i]), qv[i], dd);
            dd += __shfl_xor(dd, 1);
            dd += __shfl_xor(dd, 2);
            d[t] = dd;
        }

        float eav[8], al[8];
#pragma unroll
        for (int t = 0; t < 8; ++t) {
            eav[t] = bf2f((unsigned short)(pr[t] >> 16));
            al[t] = (t == 0 || j + t < p1) ? fmaf(eav[t], qwe, d[t]) : -3.4e38f;
        }

        float mn = m;
#pragma unroll
        for (int t = 0; t < 8; ++t) mn = fmaxf(mn, al[t]);
        float sc = exp2_hw(m - mn);
        float pe[8];
#pragma unroll
        for (int t = 0; t < 8; ++t) pe[t] = exp2_hw(al[t] - mn);

        float ls = 0.f, ss = 0.f;
#pragma unroll
        for (int t = 0; t < 8; ++t) { ls += pe[t]; ss = fmaf(pe[t], eav[t], ss); }
        l = fmaf(l, sc, ls);
        sae = fmaf(sae, sc, ss);
#pragma unroll
        for (int i = 0; i < 8; ++i) {
            float mv = 0.f;
#pragma unroll
            for (int t = 0; t < 8; ++t)
                mv = fmaf(pe[t], bf2f((unsigned short)vu[t][i]), mv);
            acc[i] = fmaf(acc[i], sc, mv);
        }
        m = mn;
    }

    float inv = 1.f / (l + 1e-16f);
    ushort8v sku = *(const ushort8v*)(skip + (size_t)node * 128 + c8);
    float o[8];
#pragma unroll
    for (int i = 0; i < 8; ++i)
        o[i] = fmaxf(fmaf(fmaf(sae, we8[i], acc[i]), inv,
                          bf2f((unsigned short)sku[i])), 0.f);

    if (BF16OUT) {
        ushort8v ov;
#pragma unroll
        for (int i = 0; i < 8; ++i) ov[i] = f2bf(o[i]);
        *(ushort8v*)((unsigned short*)outp + (size_t)node * 128 + c8) = ov;
    } else {
        float* op = (float*)outp + (size_t)node * 128 + c8;
        *(float4*)op = make_float4(o[0], o[1], o[2], o[3]);
        *(float4*)(op + 4) = make_float4(o[4], o[5], o[6], o[7]);
    }
}

extern "C" void kernel_launch(void* const* d_in, const int* in_sizes, int n_in,
                              void* d_out, int out_size, void* d_ws, size_t ws_size,
                              hipStream_t stream)
{
    const float* x   = (const float*)d_in[0];
    const int*   ei  = (const int*)d_in[1];
    const float* ea  = (const float*)d_in[2];
    const float* Wq1 = (const float*)d_in[3];  const float* bq1 = (const float*)d_in[4];
    const float* Wk1 = (const float*)d_in[5];  const float* bk1 = (const float*)d_in[6];
    const float* Wv1 = (const float*)d_in[7];  const float* bv1 = (const float*)d_in[8];
    const float* We1 = (const float*)d_in[9];
    const float* Ws1 = (const float*)d_in[10]; const float* bs1 = (const float*)d_in[11];
    const float* Wq2 = (const float*)d_in[12]; const float* bq2 = (const float*)d_in[13];
    const float* Wk2 = (const float*)d_in[14]; const float* bk2 = (const float*)d_in[15];
    const float* Wv2 = (const float*)d_in[16]; const float* bv2 = (const float*)d_in[17];
    const float* We2 = (const float*)d_in[18];
    const float* Ws2 = (const float*)d_in[19]; const float* bs2 = (const float*)d_in[20];

    const int N = in_sizes[0] / 128;
    const int E = in_sizes[1] / 2;
    const int* src = ei;
    const int* dst = ei + E;
    float* outf = (float*)d_out;

    const int nb = (N + 1023) / 1024;

    // workspace layout
    unsigned short* q  = (unsigned short*)d_ws;          // N*128 bf16
    unsigned short* kv = q + (size_t)N * 128;            // N*256 bf16 (k|v)
    unsigned short* s  = kv + (size_t)N * 256;           // N*128 bf16 skip
    unsigned short* xb = s + (size_t)N * 128;            // bf16 x / h
    unsigned short* pk = xb + (size_t)N * 128;           // 131072 (both layers)
    int*   row_ptr = (int*)(pk + 131072);                // N+1
    int*   deg     = row_ptr + (N + 1);                  // N  (memset)
    int*   incl    = deg + N;                            // N
    int*   cursor  = incl + N;                           // N
    int*   rank    = cursor + N;                         // N
    int*   bsum    = rank + N;                           // 256
    int*   bcnt    = bsum + 256;                         // 64*nb
    int*   perm    = bcnt + 64 * nb;                     // N
    unsigned* csr_pack = (unsigned*)(perm + N);          // E

    const int gE   = (E + TPB - 1) / TPB;
    const int gN16 = (N + 15) / 16;
    const int n4   = N * 128 / 4;
    const int gCv  = (n4 + TPB - 1) / TPB;
    const int nrt  = (N + 127) / 128;                    // row tiles
    const int pxi  = ((nrt + 7) / 8) * 4;                // idx slots per XCD
    const int gGm  = 8 * pxi;                            // gemm slots

    // 1) zero deg
    hipMemsetAsync(deg, 0, (size_t)N * sizeof(int), stream);
    // 2) fused hist + prepack + cvt
    hist_prep_cvt_k<<<gE + 512 + gCv, TPB, 0, stream>>>(
        dst, deg, E, gE, Wq1, Wk1, Wv1, Ws1, Wq2, Wk2, Wv2, Ws2, pk, x, xb, n4);
    // 3-5) scan chain
    scan_a_k<<<nb, TPB, 0, stream>>>(deg, N, incl, bsum, bcnt, nb, rank);
    scan_b_k<<<1, TPB, 0, stream>>>(bsum, nb, bcnt);
    finalize_k<<<nb, TPB, 0, stream>>>(incl, deg, bsum, N, row_ptr, cursor,
                                       bcnt, nb, rank, perm);
    // 6) fused scatter + layer-1 GEMM
    scatter_gemm_k<<<gE + gGm, TPB, 0, stream>>>(
        src, dst, ea, cursor, csr_pack, E, gE, pxi, nrt,
        xb, N, pk, bq1, bk1, bv1, bs1, q, kv, s);
    // 7) attn 1 (h -> bf16, reuse xb)
    node_attn_k<true><<<gN16, TPB, 0, stream>>>(q, kv, s, We1, row_ptr, csr_pack,
                                                perm, xb, N);
    // 8) layer-2 GEMM
    gemm_k<<<gGm, TPB, 0, stream>>>(pxi, nrt, xb, N, pk + 65536,
                                    bq2, bk2, bv2, bs2, q, kv, s);
    // 9) attn 2
    node_attn_k<false><<<gN16, TPB, 0, stream>>>(q, kv, s, We2, row_ptr, csr_pack,
                                                 perm, outf, N);
}

// Round 14
// 276.531 us; speedup vs baseline: 2.1484x; 1.0685x over previous
//
#include <hip/hip_runtime.h>

// TransformerConv x2 on MI355X — fused-launch 32x32 MFMA GEMM + interleaved
// CSR-scatter, degree-sorted 16-lane gather attention, 4-B CSR, bf16 skip.
// N=50000, E=800000, H=4, C=32, D=128.

#define TPB 256

typedef __attribute__((ext_vector_type(8))) short short8v;
typedef __attribute__((ext_vector_type(8))) unsigned short ushort8v;
typedef __attribute__((ext_vector_type(16))) float f32x16;

__device__ __forceinline__ unsigned short f2bf(float f) {
    unsigned u = __float_as_uint(f);
    u = (u + 0x7FFFu + ((u >> 16) & 1u)) >> 16;
    return (unsigned short)u;
}
__device__ __forceinline__ float bf2f(unsigned short s) {
    return __uint_as_float((unsigned)s << 16);
}
__device__ __forceinline__ float exp2_hw(float x) {
    float r;
    asm("v_exp_f32 %0, %1" : "=v"(r) : "v"(x));
    return r;
}

// ---- GEMM body (32x32x16), linear slot mapping: g = idx&3, row_tile = idx>>2
__device__ __forceinline__ void gemm_body(
    int idx, int nrt,
    const unsigned short* __restrict__ A, int M,
    const unsigned short* __restrict__ pack,
    const float* __restrict__ bq, const float* __restrict__ bk,
    const float* __restrict__ bv, const float* __restrict__ bs,
    unsigned short* __restrict__ oq, unsigned short* __restrict__ okv,
    unsigned short* __restrict__ os)
{
    if (idx >= nrt * 4) return;
    const int g = idx & 3;
    const int row0 = (idx >> 2) * 128;

    const int wv = threadIdx.x >> 6;
    const int lane = threadIdx.x & 63;
    const int rbase = row0 + wv * 32;
    const int arow = rbase + (lane & 31);
    const int kh = (lane >> 5) * 8;

    const short8v z8 = {0, 0, 0, 0, 0, 0, 0, 0};
    short8v a[8];
    if (arow < M) {
        const unsigned short* Ap = A + (size_t)arow * 128 + kh;
#pragma unroll
        for (int t = 0; t < 8; ++t) a[t] = *(const short8v*)(Ap + t * 16);
    } else {
#pragma unroll
        for (int t = 0; t < 8; ++t) a[t] = z8;
    }

    f32x16 acc[4];
#pragma unroll
    for (int nc = 0; nc < 4; ++nc)
#pragma unroll
        for (int r = 0; r < 16; ++r) acc[nc][r] = 0.f;

    const unsigned short* bp = pack + (size_t)g * 16384;
#pragma unroll
    for (int nc = 0; nc < 4; ++nc) {
#pragma unroll
        for (int t = 0; t < 8; ++t) {
            short8v b = *(const short8v*)(bp + (nc * 8 + t) * 512 + lane * 8);
            acc[nc] = __builtin_amdgcn_mfma_f32_32x32x16_bf16(a[t], b, acc[nc], 0, 0, 0);
        }
    }

    const float* bias = g == 0 ? bq : (g == 1 ? bk : (g == 2 ? bv : bs));
    const int col = lane & 31;
    const int rb2 = rbase + 4 * (lane >> 5);
    unsigned short* out = g == 0 ? oq : (g == 3 ? os : okv);
    const int stride = (g == 1 || g == 2) ? 256 : 128;
    const int goff = g == 2 ? 128 : 0;
#pragma unroll
    for (int nc = 0; nc < 4; ++nc) {
        float bb = bias[nc * 32 + col];
#pragma unroll
        for (int r = 0; r < 16; ++r) {
            int row = rb2 + (r & 3) + 8 * (r >> 2);
            if (row < M)
                out[(size_t)row * stride + goff + nc * 32 + col] = f2bf(acc[nc][r] + bb);
        }
    }
}

// ---- scatter body: 4 edges/thread (pipelined atomic->write chains) ----
__device__ __forceinline__ void scatter_body(
    int sb, const int* __restrict__ src, const int* __restrict__ dst,
    const float* __restrict__ ea, int* __restrict__ cursor,
    unsigned* __restrict__ csr_pack, int E)
{
    const int base = (sb * TPB + threadIdx.x) * 4;
    if (base + 3 < E) {
        int4 d4 = *(const int4*)(dst + base);
        int4 s4 = *(const int4*)(src + base);
        float4 a4 = *(const float4*)(ea + base);
        int p0 = atomicAdd(&cursor[d4.x], 1);
        int p1 = atomicAdd(&cursor[d4.y], 1);
        int p2 = atomicAdd(&cursor[d4.z], 1);
        int p3 = atomicAdd(&cursor[d4.w], 1);
        csr_pack[p0] = ((unsigned)f2bf(a4.x) << 16) | (unsigned)s4.x;
        csr_pack[p1] = ((unsigned)f2bf(a4.y) << 16) | (unsigned)s4.y;
        csr_pack[p2] = ((unsigned)f2bf(a4.z) << 16) | (unsigned)s4.z;
        csr_pack[p3] = ((unsigned)f2bf(a4.w) << 16) | (unsigned)s4.w;
    } else {
        for (int e = base; e < E; ++e) {
            int pos = atomicAdd(&cursor[dst[e]], 1);
            csr_pack[pos] = ((unsigned)f2bf(ea[e]) << 16) | (unsigned)src[e];
        }
    }
}

// ---- fused: edge histogram (4/thread) + weight prepack + x convert ----
__global__ void __launch_bounds__(TPB) hist_prep_cvt_k(
    const int* __restrict__ dst, int* __restrict__ deg, int E, int gE4,
    const float* __restrict__ Wq1, const float* __restrict__ Wk1,
    const float* __restrict__ Wv1, const float* __restrict__ Ws1,
    const float* __restrict__ Wq2, const float* __restrict__ Wk2,
    const float* __restrict__ Wv2, const float* __restrict__ Ws2,
    unsigned short* __restrict__ pack,
    const float* __restrict__ x, unsigned short* __restrict__ xb, int n4)
{
    if (blockIdx.x < (unsigned)gE4) {
        const int base = (blockIdx.x * TPB + threadIdx.x) * 4;
        if (base + 3 < E) {
            int4 d4 = *(const int4*)(dst + base);
            atomicAdd(&deg[d4.x], 1);
            atomicAdd(&deg[d4.y], 1);
            atomicAdd(&deg[d4.z], 1);
            atomicAdd(&deg[d4.w], 1);
        } else {
            for (int e = base; e < E; ++e) atomicAdd(&deg[dst[e]], 1);
        }
    } else if (blockIdx.x < (unsigned)(gE4 + 512)) {
        int i = (blockIdx.x - gE4) * TPB + threadIdx.x;   // 131072 total
        int j = i & 7, lane = (i >> 3) & 63, t = (i >> 9) & 7, nc = (i >> 12) & 3, g = (i >> 14) & 7;
        const float* Wt[8] = {Wq1, Wk1, Wv1, Ws1, Wq2, Wk2, Wv2, Ws2};
        const float* W = Wt[g];
        int kk = t * 16 + (lane >> 5) * 8 + j;
        int nn = nc * 32 + (lane & 31);
        pack[i] = f2bf(W[kk * 128 + nn]);
    } else {
        int i = (blockIdx.x - gE4 - 512) * TPB + threadIdx.x;
        if (i >= n4) return;
        float4 v = *(const float4*)(x + (size_t)i * 4);
        ushort4 o;
        o.x = f2bf(v.x); o.y = f2bf(v.y); o.z = f2bf(v.z); o.w = f2bf(v.w);
        *(ushort4*)(xb + (size_t)i * 4) = o;
    }
}

// ---------------- CSR scan chain ----------------
__global__ void __launch_bounds__(TPB) scan_a_k(const int* __restrict__ deg, int n,
                                                int* __restrict__ incl,
                                                int* __restrict__ bsum,
                                                int* __restrict__ bcnt, int nb,
                                                int* __restrict__ rank)
{
    __shared__ int ts[TPB];
    __shared__ int lhist[64];
    if (threadIdx.x < 64) lhist[threadIdx.x] = 0;
    const int base = blockIdx.x * 1024;
    int vals[4], s = 0;
#pragma unroll
    for (int j = 0; j < 4; ++j) {
        int i = base + threadIdx.x * 4 + j;
        vals[j] = (i < n) ? deg[i] : 0;
        s += vals[j];
    }
    ts[threadIdx.x] = s;
    __syncthreads();
#pragma unroll
    for (int j = 0; j < 4; ++j) {
        int i = base + threadIdx.x * 4 + j;
        if (i < n) {
            int bin = 63 - min(vals[j], 63);   // descending degree order
            rank[i] = atomicAdd(&lhist[bin], 1);
        }
    }
    for (int off = 1; off < TPB; off <<= 1) {
        int u = (threadIdx.x >= off) ? ts[threadIdx.x - off] : 0;
        __syncthreads();
        ts[threadIdx.x] += u;
        __syncthreads();
    }
    int run = ts[threadIdx.x] - s;
#pragma unroll
    for (int j = 0; j < 4; ++j) {
        run += vals[j];
        int i = base + threadIdx.x * 4 + j;
        if (i < n) incl[i] = run;
    }
    if (threadIdx.x == TPB - 1) bsum[blockIdx.x] = ts[TPB - 1];
    __syncthreads();
    if (threadIdx.x < 64) bcnt[threadIdx.x * nb + blockIdx.x] = lhist[threadIdx.x];
}

__global__ void __launch_bounds__(TPB) scan_b_k(int* __restrict__ bsum, int nb,
                                                int* __restrict__ bcnt)
{
    __shared__ int ts[TPB];
    const int t = threadIdx.x;
    int v = (t < nb) ? bsum[t] : 0;
    ts[t] = v;
    __syncthreads();
    for (int off = 1; off < TPB; off <<= 1) {
        int u = (t >= off) ? ts[t - off] : 0;
        __syncthreads();
        ts[t] += u;
        __syncthreads();
    }
    if (t < nb) bsum[t] = ts[t] - v;
    __syncthreads();

    const int total = 64 * nb;
    const int C = (total + TPB - 1) / TPB;
    int loc[32];
    int s = 0;
    for (int j = 0; j < C; ++j) {
        int i = t * C + j;
        loc[j] = (i < total) ? bcnt[i] : 0;
        s += loc[j];
    }
    __syncthreads();
    ts[t] = s;
    __syncthreads();
    for (int off = 1; off < TPB; off <<= 1) {
        int u = (t >= off) ? ts[t - off] : 0;
        __syncthreads();
        ts[t] += u;
        __syncthreads();
    }
    int run = ts[t] - s;
    for (int j = 0; j < C; ++j) {
        int i = t * C + j;
        if (i < total) bcnt[i] = run;
        run += loc[j];
    }
}

__global__ void __launch_bounds__(TPB) finalize_k(const int* __restrict__ incl,
                                                  const int* __restrict__ deg,
                                                  const int* __restrict__ bsum, int n,
                                                  int* __restrict__ row_ptr,
                                                  int* __restrict__ cursor,
                                                  const int* __restrict__ bcnt, int nb,
                                                  const int* __restrict__ rank,
                                                  int* __restrict__ perm)
{
    const int base = blockIdx.x * 1024;
    const int boff = bsum[blockIdx.x];
#pragma unroll
    for (int j = 0; j < 4; ++j) {
        int i = base + threadIdx.x * 4 + j;
        if (i < n) {
            int dg = deg[i];
            int iv = incl[i] + boff;
            row_ptr[i] = iv - dg;
            cursor[i] = iv - dg;
            if (i == n - 1) row_ptr[n] = iv;
            int bin = 63 - min(dg, 63);
            perm[bcnt[bin * nb + blockIdx.x] + rank[i]] = i;
        }
    }
}

// ---- fused: interleaved CSR scatter + layer-1 GEMM ----
// nGm = 4*nrt, nSc = ceil(E/1024). Mapping: b%3==2 -> scatter(b/3) while
// b < 3*nSc; else gemm. Keeps a 2:1 gemm:scatter resident mix so the
// scatter's random-access latency hides under MFMA compute.
__global__ void __launch_bounds__(TPB) scatter_gemm_k(
    const int* __restrict__ src, const int* __restrict__ dst,
    const float* __restrict__ ea, int* __restrict__ cursor,
    unsigned* __restrict__ csr_pack, int E, int nSc,
    int nrt,
    const unsigned short* __restrict__ A, int M,
    const unsigned short* __restrict__ pack,
    const float* __restrict__ bq, const float* __restrict__ bk,
    const float* __restrict__ bv, const float* __restrict__ bs,
    unsigned short* __restrict__ oq, unsigned short* __restrict__ okv,
    unsigned short* __restrict__ os)
{
    const int b = blockIdx.x;
    const int n3 = b / 3, r = b - n3 * 3;
    if (b < 3 * nSc) {
        if (r == 2) scatter_body(n3, src, dst, ea, cursor, csr_pack, E);
        else gemm_body(2 * n3 + r, nrt, A, M, pack, bq, bk, bv, bs, oq, okv, os);
    } else {
        gemm_body(2 * nSc + (b - 3 * nSc), nrt, A, M, pack, bq, bk, bv, bs,
                  oq, okv, os);
    }
}

__global__ void __launch_bounds__(TPB) gemm_k(
    int nrt,
    const unsigned short* __restrict__ A, int M,
    const unsigned short* __restrict__ pack,
    const float* __restrict__ bq, const float* __restrict__ bk,
    const float* __restrict__ bv, const float* __restrict__ bs,
    unsigned short* __restrict__ oq, unsigned short* __restrict__ okv,
    unsigned short* __restrict__ os)
{
    gemm_body(blockIdx.x, nrt, A, M, pack, bq, bk, bv, bs, oq, okv, os);
}

// ---- gather attention: 16 lanes/node, 8-edge unroll, degree-sorted perm ----
template <bool BF16OUT>
__global__ void __launch_bounds__(TPB) node_attn_k(
    const unsigned short* __restrict__ q, const unsigned short* __restrict__ kv,
    const unsigned short* __restrict__ skip, const float* __restrict__ We,
    const int* __restrict__ row_ptr, const unsigned* __restrict__ csr_pack,
    const int* __restrict__ perm,
    void* __restrict__ outp, int n)
{
    const int slot = blockIdx.x * 16 + (threadIdx.x >> 4);
    if (slot >= n) return;
    const int node = perm[slot];
    const int l16 = threadIdx.x & 15;
    const int c8 = l16 * 8;

    const float C2 = 0.17677669529663687f * 1.44269504088896f; // 1/sqrt(32)*log2e

    float we8[8], qv[8];
    {
        float4 wlo = *(const float4*)(We + c8);
        float4 whi = *(const float4*)(We + c8 + 4);
        we8[0] = wlo.x; we8[1] = wlo.y; we8[2] = wlo.z; we8[3] = wlo.w;
        we8[4] = whi.x; we8[5] = whi.y; we8[6] = whi.z; we8[7] = whi.w;
        ushort8v qu = *(const ushort8v*)(q + (size_t)node * 128 + c8);
#pragma unroll
        for (int i = 0; i < 8; ++i) qv[i] = bf2f((unsigned short)qu[i]) * C2;
    }

    float qwe = 0.f;
#pragma unroll
    for (int i = 0; i < 8; ++i) qwe = fmaf(qv[i], we8[i], qwe);
    qwe += __shfl_xor(qwe, 1);
    qwe += __shfl_xor(qwe, 2);

    const int p0 = row_ptr[node], p1 = row_ptr[node + 1];

    float m = -3.4e38f, l = 0.f, sae = 0.f;
    float acc[8];
#pragma unroll
    for (int i = 0; i < 8; ++i) acc[i] = 0.f;

    for (int j = p0; j < p1; j += 8) {
        const int last = p1 - 1;
        unsigned pr[8];
#pragma unroll
        for (int t = 0; t < 8; ++t) pr[t] = csr_pack[min(j + t, last)];

        ushort8v ku[8], vu[8];
#pragma unroll
        for (int t = 0; t < 8; ++t) {
            const unsigned short* b = kv + (pr[t] & 0xFFFFu) * 256u + c8;
            ku[t] = *(const ushort8v*)b;
            vu[t] = *(const ushort8v*)(b + 128);
        }

        float d[8];
#pragma unroll
        for (int t = 0; t < 8; ++t) {
            float dd = 0.f;
#pragma unroll
            for (int i = 0; i < 8; ++i)
                dd = fmaf(bf2f((unsigned short)ku[t][i]), qv[i], dd);
            dd += __shfl_xor(dd, 1);
            dd += __shfl_xor(dd, 2);
            d[t] = dd;
        }

        float eav[8], al[8];
#pragma unroll
        for (int t = 0; t < 8; ++t) {
            eav[t] = bf2f((unsigned short)(pr[t] >> 16));
            al[t] = (t == 0 || j + t < p1) ? fmaf(eav[t], qwe, d[t]) : -3.4e38f;
        }

        float mn = m;
#pragma unroll
        for (int t = 0; t < 8; ++t) mn = fmaxf(mn, al[t]);
        float sc = exp2_hw(m - mn);
        float pe[8];
#pragma unroll
        for (int t = 0; t < 8; ++t) pe[t] = exp2_hw(al[t] - mn);

        float ls = 0.f, ss = 0.f;
#pragma unroll
        for (int t = 0; t < 8; ++t) { ls += pe[t]; ss = fmaf(pe[t], eav[t], ss); }
        l = fmaf(l, sc, ls);
        sae = fmaf(sae, sc, ss);
#pragma unroll
        for (int i = 0; i < 8; ++i) {
            float mv = 0.f;
#pragma unroll
            for (int t = 0; t < 8; ++t)
                mv = fmaf(pe[t], bf2f((unsigned short)vu[t][i]), mv);
            acc[i] = fmaf(acc[i], sc, mv);
        }
        m = mn;
    }

    float inv = 1.f / (l + 1e-16f);
    ushort8v sku = *(const ushort8v*)(skip + (size_t)node * 128 + c8);
    float o[8];
#pragma unroll
    for (int i = 0; i < 8; ++i)
        o[i] = fmaxf(fmaf(fmaf(sae, we8[i], acc[i]), inv,
                          bf2f((unsigned short)sku[i])), 0.f);

    if (BF16OUT) {
        ushort8v ov;
#pragma unroll
        for (int i = 0; i < 8; ++i) ov[i] = f2bf(o[i]);
        *(ushort8v*)((unsigned short*)outp + (size_t)node * 128 + c8) = ov;
    } else {
        float* op = (float*)outp + (size_t)node * 128 + c8;
        *(float4*)op = make_float4(o[0], o[1], o[2], o[3]);
        *(float4*)(op + 4) = make_float4(o[4], o[5], o[6], o[7]);
    }
}

extern "C" void kernel_launch(void* const* d_in, const int* in_sizes, int n_in,
                              void* d_out, int out_size, void* d_ws, size_t ws_size,
                              hipStream_t stream)
{
    const float* x   = (const float*)d_in[0];
    const int*   ei  = (const int*)d_in[1];
    const float* ea  = (const float*)d_in[2];
    const float* Wq1 = (const float*)d_in[3];  const float* bq1 = (const float*)d_in[4];
    const float* Wk1 = (const float*)d_in[5];  const float* bk1 = (const float*)d_in[6];
    const float* Wv1 = (const float*)d_in[7];  const float* bv1 = (const float*)d_in[8];
    const float* We1 = (const float*)d_in[9];
    const float* Ws1 = (const float*)d_in[10]; const float* bs1 = (const float*)d_in[11];
    const float* Wq2 = (const float*)d_in[12]; const float* bq2 = (const float*)d_in[13];
    const float* Wk2 = (const float*)d_in[14]; const float* bk2 = (const float*)d_in[15];
    const float* Wv2 = (const float*)d_in[16]; const float* bv2 = (const float*)d_in[17];
    const float* We2 = (const float*)d_in[18];
    const float* Ws2 = (const float*)d_in[19]; const float* bs2 = (const float*)d_in[20];

    const int N = in_sizes[0] / 128;
    const int E = in_sizes[1] / 2;
    const int* src = ei;
    const int* dst = ei + E;
    float* outf = (float*)d_out;

    const int nb = (N + 1023) / 1024;

    // workspace layout
    unsigned short* q  = (unsigned short*)d_ws;          // N*128 bf16
    unsigned short* kv = q + (size_t)N * 128;            // N*256 bf16 (k|v)
    unsigned short* s  = kv + (size_t)N * 256;           // N*128 bf16 skip
    unsigned short* xb = s + (size_t)N * 128;            // bf16 x / h
    unsigned short* pk = xb + (size_t)N * 128;           // 131072 (both layers)
    int*   row_ptr = (int*)(pk + 131072);                // N+1
    int*   deg     = row_ptr + (N + 1);                  // N  (memset)
    int*   incl    = deg + N;                            // N
    int*   cursor  = incl + N;                           // N
    int*   rank    = cursor + N;                         // N
    int*   bsum    = rank + N;                           // 256
    int*   bcnt    = bsum + 256;                         // 64*nb
    int*   perm    = bcnt + 64 * nb;                     // N
    unsigned* csr_pack = (unsigned*)(perm + N);          // E

    const int gN16 = (N + 15) / 16;
    const int n4   = N * 128 / 4;
    const int gCv  = (n4 + TPB - 1) / TPB;
    const int gE4  = (E + 1023) / 1024;                  // 4 edges/thread blocks
    const int nrt  = (N + 127) / 128;                    // row tiles
    const int nGm  = nrt * 4;                            // gemm slots
    const int nSc  = gE4;                                // scatter blocks

    // 1) zero deg
    hipMemsetAsync(deg, 0, (size_t)N * sizeof(int), stream);
    // 2) fused hist + prepack + cvt
    hist_prep_cvt_k<<<gE4 + 512 + gCv, TPB, 0, stream>>>(
        dst, deg, E, gE4, Wq1, Wk1, Wv1, Ws1, Wq2, Wk2, Wv2, Ws2, pk, x, xb, n4);
    // 3-5) scan chain
    scan_a_k<<<nb, TPB, 0, stream>>>(deg, N, incl, bsum, bcnt, nb, rank);
    scan_b_k<<<1, TPB, 0, stream>>>(bsum, nb, bcnt);
    finalize_k<<<nb, TPB, 0, stream>>>(incl, deg, bsum, N, row_ptr, cursor,
                                       bcnt, nb, rank, perm);
    // 6) fused interleaved scatter + layer-1 GEMM
    scatter_gemm_k<<<nSc + nGm, TPB, 0, stream>>>(
        src, dst, ea, cursor, csr_pack, E, nSc, nrt,
        xb, N, pk, bq1, bk1, bv1, bs1, q, kv, s);
    // 7) attn 1 (h -> bf16, reuse xb)
    node_attn_k<true><<<gN16, TPB, 0, stream>>>(q, kv, s, We1, row_ptr, csr_pack,
                                                perm, xb, N);
    // 8) layer-2 GEMM
    gemm_k<<<nGm, TPB, 0, stream>>>(nrt, xb, N, pk + 65536,
                                    bq2, bk2, bv2, bs2, q, kv, s);
    // 9) attn 2
    node_attn_k<false><<<gN16, TPB, 0, stream>>>(q, kv, s, We2, row_ptr, csr_pack,
                                                 perm, outf, N);
}

// Round 15
// 264.195 us; speedup vs baseline: 2.2487x; 1.0467x over previous
//
#include <hip/hip_runtime.h>

// TransformerConv x2 on MI355X — fused-launch 32x32 MFMA GEMM + atomic-free
// interleaved CSR-scatter, degree-sorted 16-lane gather attention, bf16 skip.
// N=50000, E=800000, H=4, C=32, D=128.

#define TPB 256

typedef __attribute__((ext_vector_type(8))) short short8v;
typedef __attribute__((ext_vector_type(8))) unsigned short ushort8v;
typedef __attribute__((ext_vector_type(16))) float f32x16;

__device__ __forceinline__ unsigned short f2bf(float f) {
    unsigned u = __float_as_uint(f);
    u = (u + 0x7FFFu + ((u >> 16) & 1u)) >> 16;
    return (unsigned short)u;
}
__device__ __forceinline__ float bf2f(unsigned short s) {
    return __uint_as_float((unsigned)s << 16);
}
__device__ __forceinline__ float exp2_hw(float x) {
    float r;
    asm("v_exp_f32 %0, %1" : "=v"(r) : "v"(x));
    return r;
}

// ---- GEMM body (32x32x16): g = idx&3, row_tile = idx>>2 ----
__device__ __forceinline__ void gemm_body(
    int idx, int nrt,
    const unsigned short* __restrict__ A, int M,
    const unsigned short* __restrict__ pack,
    const float* __restrict__ bq, const float* __restrict__ bk,
    const float* __restrict__ bv, const float* __restrict__ bs,
    unsigned short* __restrict__ oq, unsigned short* __restrict__ okv,
    unsigned short* __restrict__ os)
{
    if (idx >= nrt * 4) return;
    const int g = idx & 3;
    const int row0 = (idx >> 2) * 128;

    const int wv = threadIdx.x >> 6;
    const int lane = threadIdx.x & 63;
    const int rbase = row0 + wv * 32;
    const int arow = rbase + (lane & 31);
    const int kh = (lane >> 5) * 8;

    const short8v z8 = {0, 0, 0, 0, 0, 0, 0, 0};
    short8v a[8];
    if (arow < M) {
        const unsigned short* Ap = A + (size_t)arow * 128 + kh;
#pragma unroll
        for (int t = 0; t < 8; ++t) a[t] = *(const short8v*)(Ap + t * 16);
    } else {
#pragma unroll
        for (int t = 0; t < 8; ++t) a[t] = z8;
    }

    f32x16 acc[4];
#pragma unroll
    for (int nc = 0; nc < 4; ++nc)
#pragma unroll
        for (int r = 0; r < 16; ++r) acc[nc][r] = 0.f;

    const unsigned short* bp = pack + (size_t)g * 16384;
#pragma unroll
    for (int nc = 0; nc < 4; ++nc) {
#pragma unroll
        for (int t = 0; t < 8; ++t) {
            short8v b = *(const short8v*)(bp + (nc * 8 + t) * 512 + lane * 8);
            acc[nc] = __builtin_amdgcn_mfma_f32_32x32x16_bf16(a[t], b, acc[nc], 0, 0, 0);
        }
    }

    const float* bias = g == 0 ? bq : (g == 1 ? bk : (g == 2 ? bv : bs));
    const int col = lane & 31;
    const int rb2 = rbase + 4 * (lane >> 5);
    unsigned short* out = g == 0 ? oq : (g == 3 ? os : okv);
    const int stride = (g == 1 || g == 2) ? 256 : 128;
    const int goff = g == 2 ? 128 : 0;
#pragma unroll
    for (int nc = 0; nc < 4; ++nc) {
        float bb = bias[nc * 32 + col];
#pragma unroll
        for (int r = 0; r < 16; ++r) {
            int row = rb2 + (r & 3) + 8 * (r >> 2);
            if (row < M)
                out[(size_t)row * stride + goff + nc * 32 + col] = f2bf(acc[nc][r] + bb);
        }
    }
}

// ---- scatter body: atomic-free. pos = row_ptr[dst] + edge_rank ----
__device__ __forceinline__ void scatter_body(
    int sb, const int* __restrict__ src, const int* __restrict__ dst,
    const float* __restrict__ ea, const int* __restrict__ row_ptr,
    const int* __restrict__ edge_rank,
    unsigned* __restrict__ csr_pack, int E)
{
    const int base = (sb * TPB + threadIdx.x) * 4;
    if (base + 3 < E) {
        int4 d4 = *(const int4*)(dst + base);
        int4 s4 = *(const int4*)(src + base);
        float4 a4 = *(const float4*)(ea + base);
        int4 r4 = *(const int4*)(edge_rank + base);
        csr_pack[row_ptr[d4.x] + r4.x] = ((unsigned)f2bf(a4.x) << 16) | (unsigned)s4.x;
        csr_pack[row_ptr[d4.y] + r4.y] = ((unsigned)f2bf(a4.y) << 16) | (unsigned)s4.y;
        csr_pack[row_ptr[d4.z] + r4.z] = ((unsigned)f2bf(a4.z) << 16) | (unsigned)s4.z;
        csr_pack[row_ptr[d4.w] + r4.w] = ((unsigned)f2bf(a4.w) << 16) | (unsigned)s4.w;
    } else {
        for (int e = base; e < E; ++e) {
            csr_pack[row_ptr[dst[e]] + edge_rank[e]] =
                ((unsigned)f2bf(ea[e]) << 16) | (unsigned)src[e];
        }
    }
}

// ---- fused: edge histogram w/ rank capture + weight prepack + x convert ----
__global__ void __launch_bounds__(TPB) hist_prep_cvt_k(
    const int* __restrict__ dst, int* __restrict__ deg,
    int* __restrict__ edge_rank, int E, int gE4,
    const float* __restrict__ Wq1, const float* __restrict__ Wk1,
    const float* __restrict__ Wv1, const float* __restrict__ Ws1,
    const float* __restrict__ Wq2, const float* __restrict__ Wk2,
    const float* __restrict__ Wv2, const float* __restrict__ Ws2,
    unsigned short* __restrict__ pack,
    const float* __restrict__ x, unsigned short* __restrict__ xb, int n4)
{
    if (blockIdx.x < (unsigned)gE4) {
        const int base = (blockIdx.x * TPB + threadIdx.x) * 4;
        if (base + 3 < E) {
            int4 d4 = *(const int4*)(dst + base);
            int4 r4;
            r4.x = atomicAdd(&deg[d4.x], 1);
            r4.y = atomicAdd(&deg[d4.y], 1);
            r4.z = atomicAdd(&deg[d4.z], 1);
            r4.w = atomicAdd(&deg[d4.w], 1);
            *(int4*)(edge_rank + base) = r4;
        } else {
            for (int e = base; e < E; ++e)
                edge_rank[e] = atomicAdd(&deg[dst[e]], 1);
        }
    } else if (blockIdx.x < (unsigned)(gE4 + 512)) {
        int i = (blockIdx.x - gE4) * TPB + threadIdx.x;   // 131072 total
        int j = i & 7, lane = (i >> 3) & 63, t = (i >> 9) & 7, nc = (i >> 12) & 3, g = (i >> 14) & 7;
        const float* Wt[8] = {Wq1, Wk1, Wv1, Ws1, Wq2, Wk2, Wv2, Ws2};
        const float* W = Wt[g];
        int kk = t * 16 + (lane >> 5) * 8 + j;
        int nn = nc * 32 + (lane & 31);
        pack[i] = f2bf(W[kk * 128 + nn]);
    } else {
        int i = (blockIdx.x - gE4 - 512) * TPB + threadIdx.x;
        if (i >= n4) return;
        float4 v = *(const float4*)(x + (size_t)i * 4);
        ushort4 o;
        o.x = f2bf(v.x); o.y = f2bf(v.y); o.z = f2bf(v.z); o.w = f2bf(v.w);
        *(ushort4*)(xb + (size_t)i * 4) = o;
    }
}

// ---------------- CSR scan chain ----------------
__global__ void __launch_bounds__(TPB) scan_a_k(const int* __restrict__ deg, int n,
                                                int* __restrict__ incl,
                                                int* __restrict__ bsum,
                                                int* __restrict__ bcnt, int nb,
                                                int* __restrict__ rank)
{
    __shared__ int ts[TPB];
    __shared__ int lhist[64];
    if (threadIdx.x < 64) lhist[threadIdx.x] = 0;
    const int base = blockIdx.x * 1024;
    int vals[4], s = 0;
#pragma unroll
    for (int j = 0; j < 4; ++j) {
        int i = base + threadIdx.x * 4 + j;
        vals[j] = (i < n) ? deg[i] : 0;
        s += vals[j];
    }
    ts[threadIdx.x] = s;
    __syncthreads();
#pragma unroll
    for (int j = 0; j < 4; ++j) {
        int i = base + threadIdx.x * 4 + j;
        if (i < n) {
            int bin = 63 - min(vals[j], 63);   // descending degree order
            rank[i] = atomicAdd(&lhist[bin], 1);
        }
    }
    for (int off = 1; off < TPB; off <<= 1) {
        int u = (threadIdx.x >= off) ? ts[threadIdx.x - off] : 0;
        __syncthreads();
        ts[threadIdx.x] += u;
        __syncthreads();
    }
    int run = ts[threadIdx.x] - s;
#pragma unroll
    for (int j = 0; j < 4; ++j) {
        run += vals[j];
        int i = base + threadIdx.x * 4 + j;
        if (i < n) incl[i] = run;
    }
    if (threadIdx.x == TPB - 1) bsum[blockIdx.x] = ts[TPB - 1];
    __syncthreads();
    if (threadIdx.x < 64) bcnt[threadIdx.x * nb + blockIdx.x] = lhist[threadIdx.x];
}

__global__ void __launch_bounds__(TPB) scan_b_k(int* __restrict__ bsum, int nb,
                                                int* __restrict__ bcnt)
{
    __shared__ int ts[TPB];
    const int t = threadIdx.x;
    int v = (t < nb) ? bsum[t] : 0;
    ts[t] = v;
    __syncthreads();
    for (int off = 1; off < TPB; off <<= 1) {
        int u = (t >= off) ? ts[t - off] : 0;
        __syncthreads();
        ts[t] += u;
        __syncthreads();
    }
    if (t < nb) bsum[t] = ts[t] - v;
    __syncthreads();

    const int total = 64 * nb;
    const int C = (total + TPB - 1) / TPB;
    int loc[32];
    int s = 0;
    for (int j = 0; j < C; ++j) {
        int i = t * C + j;
        loc[j] = (i < total) ? bcnt[i] : 0;
        s += loc[j];
    }
    __syncthreads();
    ts[t] = s;
    __syncthreads();
    for (int off = 1; off < TPB; off <<= 1) {
        int u = (t >= off) ? ts[t - off] : 0;
        __syncthreads();
        ts[t] += u;
        __syncthreads();
    }
    int run = ts[t] - s;
    for (int j = 0; j < C; ++j) {
        int i = t * C + j;
        if (i < total) bcnt[i] = run;
        run += loc[j];
    }
}

__global__ void __launch_bounds__(TPB) finalize_k(const int* __restrict__ incl,
                                                  const int* __restrict__ deg,
                                                  const int* __restrict__ bsum, int n,
                                                  int* __restrict__ row_ptr,
                                                  const int* __restrict__ bcnt, int nb,
                                                  const int* __restrict__ rank,
                                                  int* __restrict__ perm)
{
    const int base = blockIdx.x * 1024;
    const int boff = bsum[blockIdx.x];
#pragma unroll
    for (int j = 0; j < 4; ++j) {
        int i = base + threadIdx.x * 4 + j;
        if (i < n) {
            int dg = deg[i];
            int iv = incl[i] + boff;
            row_ptr[i] = iv - dg;
            if (i == n - 1) row_ptr[n] = iv;
            int bin = 63 - min(dg, 63);
            perm[bcnt[bin * nb + blockIdx.x] + rank[i]] = i;
        }
    }
}

// ---- fused: interleaved atomic-free scatter + layer-1 GEMM (2:1 mix) ----
__global__ void __launch_bounds__(TPB) scatter_gemm_k(
    const int* __restrict__ src, const int* __restrict__ dst,
    const float* __restrict__ ea, const int* __restrict__ row_ptr,
    const int* __restrict__ edge_rank,
    unsigned* __restrict__ csr_pack, int E, int nSc,
    int nrt,
    const unsigned short* __restrict__ A, int M,
    const unsigned short* __restrict__ pack,
    const float* __restrict__ bq, const float* __restrict__ bk,
    const float* __restrict__ bv, const float* __restrict__ bs,
    unsigned short* __restrict__ oq, unsigned short* __restrict__ okv,
    unsigned short* __restrict__ os)
{
    const int b = blockIdx.x;
    const int n3 = b / 3, r = b - n3 * 3;
    if (b < 3 * nSc) {
        if (r == 2) scatter_body(n3, src, dst, ea, row_ptr, edge_rank, csr_pack, E);
        else gemm_body(2 * n3 + r, nrt, A, M, pack, bq, bk, bv, bs, oq, okv, os);
    } else {
        gemm_body(2 * nSc + (b - 3 * nSc), nrt, A, M, pack, bq, bk, bv, bs,
                  oq, okv, os);
    }
}

__global__ void __launch_bounds__(TPB) gemm_k(
    int nrt,
    const unsigned short* __restrict__ A, int M,
    const unsigned short* __restrict__ pack,
    const float* __restrict__ bq, const float* __restrict__ bk,
    const float* __restrict__ bv, const float* __restrict__ bs,
    unsigned short* __restrict__ oq, unsigned short* __restrict__ okv,
    unsigned short* __restrict__ os)
{
    gemm_body(blockIdx.x, nrt, A, M, pack, bq, bk, bv, bs, oq, okv, os);
}

// ---- gather attention: 16 lanes/node, 8-edge unroll, degree-sorted perm ----
template <bool BF16OUT>
__global__ void __launch_bounds__(TPB) node_attn_k(
    const unsigned short* __restrict__ q, const unsigned short* __restrict__ kv,
    const unsigned short* __restrict__ skip, const float* __restrict__ We,
    const int* __restrict__ row_ptr, const unsigned* __restrict__ csr_pack,
    const int* __restrict__ perm,
    void* __restrict__ outp, int n)
{
    const int slot = blockIdx.x * 16 + (threadIdx.x >> 4);
    if (slot >= n) return;
    const int node = perm[slot];
    const int l16 = threadIdx.x & 15;
    const int c8 = l16 * 8;

    const float C2 = 0.17677669529663687f * 1.44269504088896f; // 1/sqrt(32)*log2e

    float we8[8], qv[8];
    {
        float4 wlo = *(const float4*)(We + c8);
        float4 whi = *(const float4*)(We + c8 + 4);
        we8[0] = wlo.x; we8[1] = wlo.y; we8[2] = wlo.z; we8[3] = wlo.w;
        we8[4] = whi.x; we8[5] = whi.y; we8[6] = whi.z; we8[7] = whi.w;
        ushort8v qu = *(const ushort8v*)(q + (size_t)node * 128 + c8);
#pragma unroll
        for (int i = 0; i < 8; ++i) qv[i] = bf2f((unsigned short)qu[i]) * C2;
    }

    float qwe = 0.f;
#pragma unroll
    for (int i = 0; i < 8; ++i) qwe = fmaf(qv[i], we8[i], qwe);
    qwe += __shfl_xor(qwe, 1);
    qwe += __shfl_xor(qwe, 2);

    const int p0 = row_ptr[node], p1 = row_ptr[node + 1];

    float m = -3.4e38f, l = 0.f, sae = 0.f;
    float acc[8];
#pragma unroll
    for (int i = 0; i < 8; ++i) acc[i] = 0.f;

    for (int j = p0; j < p1; j += 8) {
        const int last = p1 - 1;
        unsigned pr[8];
#pragma unroll
        for (int t = 0; t < 8; ++t) pr[t] = csr_pack[min(j + t, last)];

        ushort8v ku[8], vu[8];
#pragma unroll
        for (int t = 0; t < 8; ++t) {
            const unsigned short* b = kv + (pr[t] & 0xFFFFu) * 256u + c8;
            ku[t] = *(const ushort8v*)b;
            vu[t] = *(const ushort8v*)(b + 128);
        }

        float d[8];
#pragma unroll
        for (int t = 0; t < 8; ++t) {
            float dd = 0.f;
#pragma unroll
            for (int i = 0; i < 8; ++i)
                dd = fmaf(bf2f((unsigned short)ku[t][i]), qv[i], dd);
            dd += __shfl_xor(dd, 1);
            dd += __shfl_xor(dd, 2);
            d[t] = dd;
        }

        float eav[8], al[8];
#pragma unroll
        for (int t = 0; t < 8; ++t) {
            eav[t] = bf2f((unsigned short)(pr[t] >> 16));
            al[t] = (t == 0 || j + t < p1) ? fmaf(eav[t], qwe, d[t]) : -3.4e38f;
        }

        float mn = m;
#pragma unroll
        for (int t = 0; t < 8; ++t) mn = fmaxf(mn, al[t]);
        float sc = exp2_hw(m - mn);
        float pe[8];
#pragma unroll
        for (int t = 0; t < 8; ++t) pe[t] = exp2_hw(al[t] - mn);

        float ls = 0.f, ss = 0.f;
#pragma unroll
        for (int t = 0; t < 8; ++t) { ls += pe[t]; ss = fmaf(pe[t], eav[t], ss); }
        l = fmaf(l, sc, ls);
        sae = fmaf(sae, sc, ss);
#pragma unroll
        for (int i = 0; i < 8; ++i) {
            float mv = 0.f;
#pragma unroll
            for (int t = 0; t < 8; ++t)
                mv = fmaf(pe[t], bf2f((unsigned short)vu[t][i]), mv);
            acc[i] = fmaf(acc[i], sc, mv);
        }
        m = mn;
    }

    float inv = 1.f / (l + 1e-16f);
    ushort8v sku = *(const ushort8v*)(skip + (size_t)node * 128 + c8);
    float o[8];
#pragma unroll
    for (int i = 0; i < 8; ++i)
        o[i] = fmaxf(fmaf(fmaf(sae, we8[i], acc[i]), inv,
                          bf2f((unsigned short)sku[i])), 0.f);

    if (BF16OUT) {
        ushort8v ov;
#pragma unroll
        for (int i = 0; i < 8; ++i) ov[i] = f2bf(o[i]);
        *(ushort8v*)((unsigned short*)outp + (size_t)node * 128 + c8) = ov;
    } else {
        float* op = (float*)outp + (size_t)node * 128 + c8;
        *(float4*)op = make_float4(o[0], o[1], o[2], o[3]);
        *(float4*)(op + 4) = make_float4(o[4], o[5], o[6], o[7]);
    }
}

extern "C" void kernel_launch(void* const* d_in, const int* in_sizes, int n_in,
                              void* d_out, int out_size, void* d_ws, size_t ws_size,
                              hipStream_t stream)
{
    const float* x   = (const float*)d_in[0];
    const int*   ei  = (const int*)d_in[1];
    const float* ea  = (const float*)d_in[2];
    const float* Wq1 = (const float*)d_in[3];  const float* bq1 = (const float*)d_in[4];
    const float* Wk1 = (const float*)d_in[5];  const float* bk1 = (const float*)d_in[6];
    const float* Wv1 = (const float*)d_in[7];  const float* bv1 = (const float*)d_in[8];
    const float* We1 = (const float*)d_in[9];
    const float* Ws1 = (const float*)d_in[10]; const float* bs1 = (const float*)d_in[11];
    const float* Wq2 = (const float*)d_in[12]; const float* bq2 = (const float*)d_in[13];
    const float* Wk2 = (const float*)d_in[14]; const float* bk2 = (const float*)d_in[15];
    const float* Wv2 = (const float*)d_in[16]; const float* bv2 = (const float*)d_in[17];
    const float* We2 = (const float*)d_in[18];
    const float* Ws2 = (const float*)d_in[19]; const float* bs2 = (const float*)d_in[20];

    const int N = in_sizes[0] / 128;
    const int E = in_sizes[1] / 2;
    const int* src = ei;
    const int* dst = ei + E;
    float* outf = (float*)d_out;

    const int nb = (N + 1023) / 1024;

    // workspace layout
    unsigned short* q  = (unsigned short*)d_ws;          // N*128 bf16
    unsigned short* kv = q + (size_t)N * 128;            // N*256 bf16 (k|v)
    unsigned short* s  = kv + (size_t)N * 256;           // N*128 bf16 skip
    unsigned short* xb = s + (size_t)N * 128;            // bf16 x / h
    unsigned short* pk = xb + (size_t)N * 128;           // 131072 (both layers)
    int*   row_ptr = (int*)(pk + 131072);                // N+1
    int*   deg     = row_ptr + (N + 1);                  // N  (memset)
    int*   incl    = deg + N;                            // N
    int*   rank    = incl + N;                           // N
    int*   bsum    = rank + N;                           // 256
    int*   bcnt    = bsum + 256;                         // 64*nb
    int*   perm    = bcnt + 64 * nb;                     // N
    int*   edge_rank = perm + N;                         // E
    unsigned* csr_pack = (unsigned*)(edge_rank + E);     // E

    const int gN16 = (N + 15) / 16;
    const int n4   = N * 128 / 4;
    const int gCv  = (n4 + TPB - 1) / TPB;
    const int gE4  = (E + 1023) / 1024;                  // 4 edges/thread blocks
    const int nrt  = (N + 127) / 128;                    // row tiles
    const int nGm  = nrt * 4;                            // gemm slots
    const int nSc  = gE4;                                // scatter blocks

    // 1) zero deg
    hipMemsetAsync(deg, 0, (size_t)N * sizeof(int), stream);
    // 2) fused hist(+rank) + prepack + cvt
    hist_prep_cvt_k<<<gE4 + 512 + gCv, TPB, 0, stream>>>(
        dst, deg, edge_rank, E, gE4,
        Wq1, Wk1, Wv1, Ws1, Wq2, Wk2, Wv2, Ws2, pk, x, xb, n4);
    // 3-5) scan chain
    scan_a_k<<<nb, TPB, 0, stream>>>(deg, N, incl, bsum, bcnt, nb, rank);
    scan_b_k<<<1, TPB, 0, stream>>>(bsum, nb, bcnt);
    finalize_k<<<nb, TPB, 0, stream>>>(incl, deg, bsum, N, row_ptr,
                                       bcnt, nb, rank, perm);
    // 6) fused interleaved atomic-free scatter + layer-1 GEMM
    scatter_gemm_k<<<nSc + nGm, TPB, 0, stream>>>(
        src, dst, ea, row_ptr, edge_rank, csr_pack, E, nSc, nrt,
        xb, N, pk, bq1, bk1, bv1, bs1, q, kv, s);
    // 7) attn 1 (h -> bf16, reuse xb)
    node_attn_k<true><<<gN16, TPB, 0, stream>>>(q, kv, s, We1, row_ptr, csr_pack,
                                                perm, xb, N);
    // 8) layer-2 GEMM
    gemm_k<<<nGm, TPB, 0, stream>>>(nrt, xb, N, pk + 65536,
                                    bq2, bk2, bv2, bs2, q, kv, s);
    // 9) attn 2
    node_attn_k<false><<<gN16, TPB, 0, stream>>>(q, kv, s, We2, row_ptr, csr_pack,
                                                 perm, outf, N);
}